// Round 11
// baseline (681.483 us; speedup 1.0000x reference)
//
#include <hip/hip_runtime.h>
#include <hip/hip_bf16.h>

#define NNODES 10000
#define TLEN 24
#define INDIM 16
#define HID 128
#define GDIM 512   // 4*HID (LSTM gates) == HEADS*HID (GAT)

typedef __hip_bfloat16 bf16;
typedef short v8s __attribute__((ext_vector_type(8)));
typedef float v4f __attribute__((ext_vector_type(4)));

__device__ inline float u2f(unsigned u){ return __uint_as_float(u); }

__device__ inline void unpack8(uint4 v, float* f){
  f[0]=u2f(v.x<<16); f[1]=u2f(v.x&0xFFFF0000u);
  f[2]=u2f(v.y<<16); f[3]=u2f(v.y&0xFFFF0000u);
  f[4]=u2f(v.z<<16); f[5]=u2f(v.z&0xFFFF0000u);
  f[6]=u2f(v.w<<16); f[7]=u2f(v.w&0xFFFF0000u);
}

// fast device transcendentals (v_exp_f32 + v_rcp_f32; inf-safe)
__device__ inline float fsig(float x){
  return __builtin_amdgcn_rcpf(1.f + __expf(-x));
}
__device__ inline float ftanh(float x){
  float t = __expf(-2.f*fabsf(x));           // in (0,1], no overflow
  float r = (1.f - t) * __builtin_amdgcn_rcpf(1.f + t);
  return copysignf(r, x);
}

// ---------------------------------------------------------------------------
// Convert 11 f32 weight matrices (MFMA B-operands) to bf16.
// Order: wih0,whh0,wih1,whh1, wl0,wr0,pw0, wl1,wr1,pw1 (65536 ea), mow0 (16384).
// ---------------------------------------------------------------------------
__global__ __launch_bounds__(256) void conv_w_k(
    const float* s0, const float* s1, const float* s2, const float* s3,
    const float* s4, const float* s5, const float* s6, const float* s7,
    const float* s8, const float* s9, const float* s10, bf16* __restrict__ dst)
{
  int idx = blockIdx.x*256 + threadIdx.x;
  if (idx >= 671744) return;
  int c = idx >> 16;
  float v;
  if (c < 10){
    const float* srcs[10] = {s0,s1,s2,s3,s4,s5,s6,s7,s8,s9};
    v = srcs[c][idx & 0xFFFF];
  } else {
    v = s10[idx - 655360];
  }
  dst[idx] = __float2bfloat16(v);
}

// ---------------------------------------------------------------------------
// Prep: folded MLP-in weights (f32), presummed LSTM biases, concat GAT biases.
// ---------------------------------------------------------------------------
__global__ void prep_w_k(
    const float* __restrict__ miw0, const float* __restrict__ mib0,
    const float* __restrict__ miw1, const float* __restrict__ mib1,
    const float* __restrict__ bih0, const float* __restrict__ bhh0,
    const float* __restrict__ bih1, const float* __restrict__ bhh1,
    const float* __restrict__ bl0, const float* __restrict__ br0,
    const float* __restrict__ bl1, const float* __restrict__ br1,
    float* __restrict__ Wp, float* __restrict__ bp,
    float* __restrict__ bsum, float* __restrict__ gblr)
{
  int t = threadIdx.x;
  for (int idx = t; idx < HID*INDIM; idx += 256){
    int j = idx >> 4, d = idx & 15;
    float s = 0.f;
    for (int k=0;k<HID;k++) s += miw1[j*HID+k] * miw0[k*INDIM+d];
    Wp[idx] = s;
  }
  for (int j = t; j < HID; j += 256){
    float s = mib1[j];
    for (int k=0;k<HID;k++) s += miw1[j*HID+k] * mib0[k];
    bp[j] = s;
  }
  for (int i = t; i < GDIM; i += 256){
    bsum[i]        = bih0[i] + bhh0[i];
    bsum[GDIM + i] = bih1[i] + bhh1[i];
  }
  for (int i = t; i < GDIM; i += 256){
    gblr[i]          = bl0[i];
    gblr[GDIM + i]   = br0[i];
    gblr[1024 + i]   = bl1[i];
    gblr[1536 + i]   = br1[i];
  }
}

// ---------------------------------------------------------------------------
// MLP-in: 64-row x-tile in LDS, W row in registers. Grid 3750.
// ---------------------------------------------------------------------------
__global__ __launch_bounds__(256) void mlp_in_k(
    const float* __restrict__ x, const float* __restrict__ Wp,
    const float* __restrict__ bp, bf16* __restrict__ X0)
{
  __shared__ __align__(16) float xs[64*16];
  const int tid = threadIdx.x;
  const int m0 = blockIdx.x*64;
  {
    int row = tid >> 2, q = tid & 3;
    int m = m0 + row;
    int t = m / NNODES, n = m - t*NNODES;
    float4 v = *(const float4*)(x + ((size_t)n*TLEN + t)*INDIM + q*4);
    *(float4*)(xs + row*16 + q*4) = v;
  }
  const int j = tid & 127;
  const int half = tid >> 7;
  const float* wr = Wp + j*INDIM;
  float4 w0 = *(const float4*)(wr);
  float4 w1 = *(const float4*)(wr + 4);
  float4 w2 = *(const float4*)(wr + 8);
  float4 w3 = *(const float4*)(wr + 12);
  float bj = bp[j];
  __syncthreads();
  #pragma unroll 4
  for (int mi=0; mi<32; mi++){
    int row = mi*2 + half;
    const float* xr = xs + row*16;
    float4 a0 = *(const float4*)(xr);
    float4 a1 = *(const float4*)(xr + 4);
    float4 a2 = *(const float4*)(xr + 8);
    float4 a3 = *(const float4*)(xr + 12);
    float s = bj
      + a0.x*w0.x + a0.y*w0.y + a0.z*w0.z + a0.w*w0.w
      + a1.x*w1.x + a1.y*w1.y + a1.z*w1.z + a1.w*w1.w
      + a2.x*w2.x + a2.y*w2.y + a2.z*w2.z + a2.w*w2.w
      + a3.x*w3.x + a3.y*w3.y + a3.z*w3.z + a3.w*w3.w;
    s = s > 0.f ? s : 0.f;
    X0[(size_t)(m0+row)*HID + j] = __float2bfloat16(s);
  }
}

// ---------------------------------------------------------------------------
// LSTM, one layer, 24 steps. Register-resident weights, fast transcendentals,
// double-buffered LDS h, rolled t-loop (I-cache). Loop re-ordered so the
// ih-MFMAs of step t+1 (independent of h[t]) issue BEFORE the barrier —
// filling the MFMA pipe under other waves' trans epilogues and absorbing
// wave skew; global h[t-1] store deferred to post-barrier at top of t.
// ---------------------------------------------------------------------------
template<int WRITE_ALL>
__global__ __launch_bounds__(512, 2) void lstm_half(
    const bf16* __restrict__ Xin, const bf16* __restrict__ Wih,
    const bf16* __restrict__ Whh, const float* __restrict__ bias,
    bf16* __restrict__ out)
{
  __shared__ __align__(16) bf16 hsA[48*136];
  __shared__ __align__(16) bf16 hsB[48*136];
  const int tid = threadIdx.x;
  const int lane = tid & 63, w = tid >> 6;
  const int r16 = lane & 15, quad = lane >> 4;
  const int m0 = blockIdx.x*48;

  // weights -> registers (once)
  v8s wbi[4][4], wbh[4][4];
  #pragma unroll
  for (int g=0; g<4; g++)
    #pragma unroll
    for (int kc=0; kc<4; kc++){
      size_t o = (size_t)(g*HID + w*16 + r16)*HID + kc*32 + quad*8;
      wbi[g][kc] = *(const v8s*)(Wih + o);
      wbh[g][kc] = *(const v8s*)(Whh + o);
    }
  float bg[4];
  #pragma unroll
  for (int g=0; g<4; g++) bg[g] = bias[g*HID + w*16 + r16];

  // clamped A-row offsets
  size_t rowoff[3];
  #pragma unroll
  for (int mi=0; mi<3; mi++){
    int r = m0 + mi*16 + r16;
    rowoff[mi] = (size_t)(r < NNODES ? r : NNODES-1) * HID;
  }

  float c[12];
  #pragma unroll
  for (int i=0;i<12;i++) c[i] = 0.f;

  // zero both h buffers (t=0 reads hsB)
  for (int i = tid; i < 816; i += 512){
    *(uint4*)((char*)hsA + i*16) = make_uint4(0,0,0,0);
    *(uint4*)((char*)hsB + i*16) = make_uint4(0,0,0,0);
  }

  // preload X[0] fragments
  v8s ax[3][4];
  #pragma unroll
  for (int kc=0; kc<4; kc++)
    #pragma unroll
    for (int mi=0; mi<3; mi++)
      ax[mi][kc] = *(const v8s*)(Xin + rowoff[mi] + kc*32 + quad*8);

  __syncthreads();   // publish zeroed h buffers

  // prologue: ih(0) into acc; then prefetch X[1]
  v4f acc[3][4];
  #pragma unroll
  for (int mi=0;mi<3;mi++)
    #pragma unroll
    for (int g=0;g<4;g++) acc[mi][g] = (v4f)0.f;
  #pragma unroll
  for (int kc=0; kc<4; kc++)
    #pragma unroll
    for (int mi=0;mi<3;mi++)
      #pragma unroll
      for (int g=0;g<4;g++)
        acc[mi][g] = __builtin_amdgcn_mfma_f32_16x16x32_bf16(ax[mi][kc], wbi[g][kc], acc[mi][g], 0, 0, 0);
  #pragma unroll
  for (int kc=0; kc<4; kc++)
    #pragma unroll
    for (int mi=0; mi<3; mi++)
      ax[mi][kc] = *(const v8s*)(Xin + (size_t)NNODES*HID + rowoff[mi] + kc*32 + quad*8);

  #pragma unroll 1
  for (int t=0; t<TLEN; t++){
    bf16* hrd = (t & 1) ? hsA : hsB;
    bf16* hwr = (t & 1) ? hsB : hsA;

    // deferred global store of h[t-1] (published by previous barrier; hrd
    // holds h[t-1] and is read-only this whole iteration)
    if (WRITE_ALL && t > 0){
      bf16* dst = (bf16*)(Xin + (size_t)(t-1)*NNODES*HID);  // own rows only
      for (int i = tid; i < 768; i += 512){
        int row = i >> 4, c8 = (i & 15) * 8;
        if (m0 + row < NNODES)
          *(uint4*)(dst + (size_t)(m0+row)*HID + c8) = *(const uint4*)(hrd + row*136 + c8);
      }
    }

    // hh from LDS h[t-1] (acc already holds ih(t))
    #pragma unroll
    for (int kc=0; kc<4; kc++){
      v8s av[3];
      #pragma unroll
      for (int mi=0;mi<3;mi++)
        av[mi] = *(const v8s*)(hrd + (mi*16 + r16)*136 + kc*32 + quad*8);
      #pragma unroll
      for (int mi=0;mi<3;mi++)
        #pragma unroll
        for (int g=0;g<4;g++)
          acc[mi][g] = __builtin_amdgcn_mfma_f32_16x16x32_bf16(av[mi], wbh[g][kc], acc[mi][g], 0, 0, 0);
    }

    // epilogue: h[t] -> hwr (different buffer than hrd -> no WAR hazard)
    #pragma unroll
    for (int mi=0;mi<3;mi++)
      #pragma unroll
      for (int r=0;r<4;r++){
        int lrow = mi*16 + quad*4 + r;
        float iv = acc[mi][0][r] + bg[0];
        float fv = acc[mi][1][r] + bg[1];
        float gv = acc[mi][2][r] + bg[2];
        float ov = acc[mi][3][r] + bg[3];
        float ig = fsig(iv), fg = fsig(fv);
        float gg = ftanh(gv), og = fsig(ov);
        int ci = mi*4 + r;
        float cn = fg*c[ci] + ig*gg;
        c[ci] = cn;
        hwr[lrow*136 + w*16 + r16] = __float2bfloat16(og*ftanh(cn));
      }

    // ih(t+1) + prefetch X[t+2] BEFORE the barrier (no h dependency):
    // overlaps other waves' trans epilogues, absorbs skew.
    if (t+1 < TLEN){
      #pragma unroll
      for (int mi=0;mi<3;mi++)
        #pragma unroll
        for (int g=0;g<4;g++) acc[mi][g] = (v4f)0.f;
      #pragma unroll
      for (int kc=0; kc<4; kc++)
        #pragma unroll
        for (int mi=0;mi<3;mi++)
          #pragma unroll
          for (int g=0;g<4;g++)
            acc[mi][g] = __builtin_amdgcn_mfma_f32_16x16x32_bf16(ax[mi][kc], wbi[g][kc], acc[mi][g], 0, 0, 0);
      int tn = t+2 < TLEN ? t+2 : TLEN-1;
      const bf16* Xn = Xin + (size_t)tn*NNODES*HID;
      #pragma unroll
      for (int kc=0; kc<4; kc++)
        #pragma unroll
        for (int mi=0; mi<3; mi++)
          ax[mi][kc] = *(const v8s*)(Xn + rowoff[mi] + kc*32 + quad*8);
    }

    __syncthreads();   // publish h[t]; gates next hh
  }

  // final h[23] lives in hsB (t=23 wrote hwr=hsB)
  if (WRITE_ALL){
    bf16* dst = (bf16*)(Xin + (size_t)(TLEN-1)*NNODES*HID);
    for (int i = tid; i < 768; i += 512){
      int row = i >> 4, c8 = (i & 15) * 8;
      if (m0 + row < NNODES)
        *(uint4*)(dst + (size_t)(m0+row)*HID + c8) = *(const uint4*)(hsB + row*136 + c8);
    }
  } else {
    for (int i = tid; i < 768; i += 512){
      int row = i >> 4, c8 = (i & 15) * 8;
      if (m0 + row < NNODES)
        *(uint4*)(out + (size_t)(m0+row)*HID + c8) = *(const uint4*)(hsB + row*136 + c8);
    }
  }
}

// ---------------------------------------------------------------------------
// Generic bf16 GEMM: C[M,N] = act(A[M,K] @ B[N,K]^T + bias_f32[N]), bf16 out.
// 128x128 tile, 256 thr.
// ---------------------------------------------------------------------------
template<int ACT>
__global__ __launch_bounds__(256) void gemm_bt(
    const bf16* __restrict__ A, const bf16* __restrict__ B,
    const float* __restrict__ bias, bf16* __restrict__ C,
    int M, int N, int K)
{
  __shared__ __align__(16) bf16 As[128*40];
  __shared__ __align__(16) bf16 Bs[128*40];
  const int tid = threadIdx.x;
  const int m0 = blockIdx.x*128, n0 = blockIdx.y*128;
  const int lane = tid & 63, wave = tid >> 6;
  const int r16 = lane & 15, quad = lane >> 4;

  v4f acc[2][8];
  #pragma unroll
  for (int a=0;a<2;a++)
    #pragma unroll
    for (int b=0;b<8;b++) acc[a][b] = (v4f)0.f;

  for (int k0=0; k0<K; k0+=32){
    #pragma unroll
    for (int i=0;i<2;i++){
      int li = tid + i*256;
      int row = li >> 2, q4 = li & 3;
      uint4 va = make_uint4(0,0,0,0);
      int gm = m0 + row;
      if (gm < M) va = *(const uint4*)(A + (size_t)gm*K + k0 + q4*8);
      *(uint4*)(As + row*40 + q4*8) = va;
      uint4 vb = make_uint4(0,0,0,0);
      int gn = n0 + row;
      if (gn < N) vb = *(const uint4*)(B + (size_t)gn*K + k0 + q4*8);
      *(uint4*)(Bs + row*40 + q4*8) = vb;
    }
    __syncthreads();
    v8s av[2], bv[8];
    #pragma unroll
    for (int mi=0;mi<2;mi++)
      av[mi] = *(const v8s*)(As + (wave*32 + mi*16 + r16)*40 + quad*8);
    #pragma unroll
    for (int ni=0;ni<8;ni++)
      bv[ni] = *(const v8s*)(Bs + (ni*16 + r16)*40 + quad*8);
    #pragma unroll
    for (int mi=0;mi<2;mi++)
      #pragma unroll
      for (int ni=0;ni<8;ni++)
        acc[mi][ni] = __builtin_amdgcn_mfma_f32_16x16x32_bf16(av[mi], bv[ni], acc[mi][ni], 0, 0, 0);
    __syncthreads();
  }

  #pragma unroll
  for (int mi=0;mi<2;mi++){
    #pragma unroll
    for (int r=0;r<4;r++){
      int row = m0 + wave*32 + mi*16 + quad*4 + r;
      if (row >= M) continue;
      #pragma unroll
      for (int ni=0;ni<8;ni++){
        int col = n0 + ni*16 + r16;
        float v = acc[mi][ni][r] + bias[col];
        if (ACT == 1) v = v > 0.f ? v : 0.f;
        C[(size_t)row*N + col] = __float2bfloat16(v);
      }
    }
  }
}

// ---------------------------------------------------------------------------
// 64-row-tile GEMM for N=128 outputs (projection / mlp-out): 2x the blocks
// of the 128-tile for small-M work. Same K-order -> bit-identical results.
// ---------------------------------------------------------------------------
template<int ACT>
__global__ __launch_bounds__(256) void gemm_bt64(
    const bf16* __restrict__ A, const bf16* __restrict__ B,
    const float* __restrict__ bias, bf16* __restrict__ C,
    int M, int K)   // N == 128
{
  __shared__ __align__(16) bf16 As[64*40];
  __shared__ __align__(16) bf16 Bs[128*40];
  const int tid = threadIdx.x;
  const int m0 = blockIdx.x*64;
  const int lane = tid & 63, wave = tid >> 6;
  const int r16 = lane & 15, quad = lane >> 4;

  v4f acc[8];
  #pragma unroll
  for (int b=0;b<8;b++) acc[b] = (v4f)0.f;

  for (int k0=0; k0<K; k0+=32){
    {
      int row = tid >> 2, q4 = tid & 3;
      uint4 va = make_uint4(0,0,0,0);
      int gm = m0 + row;
      if (gm < M) va = *(const uint4*)(A + (size_t)gm*K + k0 + q4*8);
      *(uint4*)(As + row*40 + q4*8) = va;
    }
    #pragma unroll
    for (int i=0;i<2;i++){
      int li = tid + i*256;
      int row = li >> 2, q4 = li & 3;
      uint4 vb = *(const uint4*)(B + (size_t)row*K + k0 + q4*8);
      *(uint4*)(Bs + row*40 + q4*8) = vb;
    }
    __syncthreads();
    v8s av, bv[8];
    av = *(const v8s*)(As + (wave*16 + r16)*40 + quad*8);
    #pragma unroll
    for (int ni=0;ni<8;ni++)
      bv[ni] = *(const v8s*)(Bs + (ni*16 + r16)*40 + quad*8);
    #pragma unroll
    for (int ni=0;ni<8;ni++)
      acc[ni] = __builtin_amdgcn_mfma_f32_16x16x32_bf16(av, bv[ni], acc[ni], 0, 0, 0);
    __syncthreads();
  }

  #pragma unroll
  for (int r=0;r<4;r++){
    int row = m0 + wave*16 + quad*4 + r;
    if (row >= M) continue;
    #pragma unroll
    for (int ni=0;ni<8;ni++){
      int col = ni*16 + r16;
      float v = acc[ni][r] + bias[col];
      if (ACT == 1) v = v > 0.f ? v : 0.f;
      C[(size_t)row*HID + col] = __float2bfloat16(v);
    }
  }
}

// ---------------------------------------------------------------------------
// CSR build (payload = resolved src id)
// ---------------------------------------------------------------------------
__global__ void deg_count_k(const int* __restrict__ dst, int* __restrict__ deg, int E){
  int e = blockIdx.x*256 + threadIdx.x;
  if (e < E){
    unsigned d = (unsigned)dst[e];
    if (d < (unsigned)NNODES) atomicAdd(&deg[d], 1);
  }
}

__global__ void scan_k(const int* __restrict__ deg, int* __restrict__ offs,
                       int* __restrict__ cursor, int n)
{
  __shared__ int part[256];
  __shared__ int base[256];
  int t = threadIdx.x;
  int lo = t*40, hi = lo+40;
  if (lo > n) lo = n;
  if (hi > n) hi = n;
  int s = 0;
  for (int i=lo;i<hi;i++) s += deg[i];
  part[t] = s;
  __syncthreads();
  if (t == 0){
    int run=0;
    for (int i=0;i<256;i++){ base[i]=run; run+=part[i]; }
    offs[n] = run;
  }
  __syncthreads();
  int run = base[t];
  for (int i=lo;i<hi;i++){ offs[i]=run; cursor[i]=run; run += deg[i]; }
}

__global__ void fill_k(const int* __restrict__ src, const int* __restrict__ dst,
                       int* __restrict__ cursor, int* __restrict__ srcs, int E){
  int e = blockIdx.x*256 + threadIdx.x;
  if (e < E){
    unsigned d = (unsigned)dst[e];
    if (d < (unsigned)NNODES){
      int p = atomicAdd(&cursor[d], 1);
      unsigned s = (unsigned)src[e];
      srcs[p] = (s < (unsigned)NNODES) ? (int)s : 0;
    }
  }
}

// ---------------------------------------------------------------------------
// GATv2 online-softmax fused score+aggregate. 1 wave/dst node.
// ---------------------------------------------------------------------------
__global__ __launch_bounds__(256) void gat_onl(
    const int* __restrict__ offs, const int* __restrict__ srcs,
    const bf16* __restrict__ xc, const float* __restrict__ att,
    const float* __restrict__ gbias, bf16* __restrict__ agg)
{
  int d = blockIdx.x*4 + (threadIdx.x >> 6);
  if (d >= NNODES) return;
  int lane = threadIdx.x & 63;
  float fr[8];
  unpack8(*(const uint4*)(xc + (size_t)d*1024 + 512 + lane*8), fr);
  float4 a0 = *(const float4*)(att + lane*8);
  float4 a1 = *(const float4*)(att + lane*8 + 4);
  float fa[8] = {a0.x,a0.y,a0.z,a0.w,a1.x,a1.y,a1.z,a1.w};
  int i0 = offs[d], i1 = offs[d+1];

  float m = -3.4e38f, den = 0.f;
  float acc[8] = {0,0,0,0,0,0,0,0};
  for (int i=i0; i<i1; i++){
    int s = srcs[i];
    float fl[8];
    unpack8(*(const uint4*)(xc + (size_t)s*1024 + lane*8), fl);
    float p = 0.f;
    #pragma unroll
    for (int q=0;q<8;q++){
      float v = fl[q] + fr[q];
      v = v > 0.f ? v : 0.2f*v;
      p += v*fa[q];
    }
    p += __shfl_xor(p, 1); p += __shfl_xor(p, 2);
    p += __shfl_xor(p, 4); p += __shfl_xor(p, 8);
    float mn = fmaxf(m, p);
    float corr = __expf(m - mn);
    float w = __expf(p - mn);
    den = den*corr + w;
    #pragma unroll
    for (int q=0;q<8;q++) acc[q] = acc[q]*corr + w*fl[q];
    m = mn;
  }
  float r = 1.f/(den + 1e-16f);
  float4 b0 = *(const float4*)(gbias + lane*8);
  float4 b1 = *(const float4*)(gbias + lane*8 + 4);
  float fb[8] = {b0.x,b0.y,b0.z,b0.w,b1.x,b1.y,b1.z,b1.w};
  #pragma unroll
  for (int q=0;q<8;q++)
    agg[(size_t)d*GDIM + lane*8 + q] = __float2bfloat16(acc[q]*r + fb[q]);
}

// ---------------------------------------------------------------------------
// Final linear (N=24): f32 weights, f32 out.
// ---------------------------------------------------------------------------
__global__ __launch_bounds__(256) void mlp_final_k(
    const bf16* __restrict__ a, const float* __restrict__ w,
    const float* __restrict__ b, float* __restrict__ out)
{
  int g = blockIdx.x*256 + threadIdx.x;
  if (g >= NNODES*24) return;
  int j = g % 24;
  int row = g / 24;
  const bf16* ar = a + (size_t)row*HID;
  const float* wr = w + (size_t)j*HID;
  float s = b[j];
  for (int k=0;k<HID;k+=8){
    float fa[8];
    unpack8(*(const uint4*)(ar+k), fa);
    float4 w0 = *(const float4*)(wr + k);
    float4 w1 = *(const float4*)(wr + k + 4);
    s += fa[0]*w0.x + fa[1]*w0.y + fa[2]*w0.z + fa[3]*w0.w
       + fa[4]*w1.x + fa[5]*w1.y + fa[6]*w1.z + fa[7]*w1.w;
  }
  out[g] = s;
}

// ---------------------------------------------------------------------------

extern "C" void kernel_launch(void* const* d_in, const int* in_sizes, int n_in,
                              void* d_out, int out_size, void* d_ws, size_t ws_size,
                              hipStream_t stream)
{
  const float* x   = (const float*)d_in[0];
  const int*   ei  = (const int*)d_in[1];
  const int E = in_sizes[1] / 2;
  const int* srcp = ei;
  const int* dstp = ei + E;

  const float* miw0 = (const float*)d_in[2];
  const float* mib0 = (const float*)d_in[3];
  const float* miw1 = (const float*)d_in[4];
  const float* mib1 = (const float*)d_in[5];
  const float* wih0 = (const float*)d_in[6];
  const float* whh0 = (const float*)d_in[7];
  const float* bih0 = (const float*)d_in[8];
  const float* bhh0 = (const float*)d_in[9];
  const float* wih1 = (const float*)d_in[10];
  const float* whh1 = (const float*)d_in[11];
  const float* bih1 = (const float*)d_in[12];
  const float* bhh1 = (const float*)d_in[13];
  const float* g_wl[2]   = {(const float*)d_in[14], (const float*)d_in[22]};
  const float* g_bl[2]   = {(const float*)d_in[15], (const float*)d_in[23]};
  const float* g_wr[2]   = {(const float*)d_in[16], (const float*)d_in[24]};
  const float* g_br[2]   = {(const float*)d_in[17], (const float*)d_in[25]};
  const float* g_att[2]  = {(const float*)d_in[18], (const float*)d_in[26]};
  const float* g_bias[2] = {(const float*)d_in[19], (const float*)d_in[27]};
  const float* g_pw[2]   = {(const float*)d_in[20], (const float*)d_in[28]};
  const float* g_pb[2]   = {(const float*)d_in[21], (const float*)d_in[29]};
  const float* mow0 = (const float*)d_in[30];
  const float* mob0 = (const float*)d_in[31];
  const float* mow1 = (const float*)d_in[32];
  const float* mob1 = (const float*)d_in[33];
  (void)n_in; (void)out_size; (void)ws_size;

  // ---- workspace layout ----
  char* base = (char*)d_ws;
  size_t off = 0;
  auto carve = [&](size_t n)->char*{
    char* p = base + off;
    off = (off + n + 255) & ~(size_t)255;
    return p;
  };
  char*  X0r = carve((size_t)TLEN*NNODES*HID*2);   // 61,440,000
  bf16*  zf  = (bf16*)carve((size_t)NNODES*HID*2);
  float* Wp  = (float*)carve(HID*INDIM*4);
  float* bp  = (float*)carve(HID*4);
  float* bsum= (float*)carve(2*GDIM*4);
  float* gblr= (float*)carve(2*1024*4);
  bf16*  wbf = (bf16*)carve((size_t)671744*2);
  int*   offsb = (int*)carve((size_t)(NNODES+1)*4);
  int*   curs  = (int*)carve((size_t)NNODES*4);
  int*   srcs  = (int*)carve((size_t)E*4);
  int*   deg   = (int*)carve((size_t)NNODES*4);
  bf16*  agg   = (bf16*)carve((size_t)NNODES*GDIM*2);

  // wbf sub-pointers (conv_w_k chunk order)
  const bf16* wih0b = wbf + 0;
  const bf16* whh0b = wbf + 65536;
  const bf16* wih1b = wbf + 131072;
  const bf16* whh1b = wbf + 196608;
  const bf16* wlr0b = wbf + 262144;   // wl0|wr0 contiguous [1024,128]
  const bf16* pw0b  = wbf + 393216;
  const bf16* wlr1b = wbf + 458752;   // wl1|wr1 contiguous
  const bf16* pw1b  = wbf + 589824;
  const bf16* mow0b = wbf + 655360;
  const bf16* wlrb[2] = {wlr0b, wlr1b};
  const bf16* pwb[2]  = {pw0b, pw1b};

  // X0 region aliases (holds X0, then h1 in-place, dead after LSTM)
  bf16* X0 = (bf16*)X0r;
  bf16* xc = (bf16*)X0r;                      // [10000,1024] = xl|xr
  bf16* z2 = (bf16*)(X0r + 20480000);
  bf16* z3 = (bf16*)(X0r + 23040000);
  bf16* o0 = (bf16*)(X0r + 25600000);

  // ---- prep ----
  conv_w_k<<<2624, 256, 0, stream>>>(wih0, whh0, wih1, whh1,
                                     g_wl[0], g_wr[0], g_pw[0],
                                     g_wl[1], g_wr[1], g_pw[1], mow0, wbf);
  prep_w_k<<<1, 256, 0, stream>>>(miw0, mib0, miw1, mib1,
                                  bih0, bhh0, bih1, bhh1,
                                  g_bl[0], g_br[0], g_bl[1], g_br[1],
                                  Wp, bp, bsum, gblr);
  hipMemsetAsync(deg, 0, (size_t)NNODES*4, stream);

  // ---- MLP in ----
  mlp_in_k<<<(TLEN*NNODES)/64, 256, 0, stream>>>(x, Wp, bp, X0);

  // ---- CSR build ----
  deg_count_k<<<(E+255)/256, 256, 0, stream>>>(dstp, deg, E);
  scan_k<<<1, 256, 0, stream>>>(deg, offsb, curs, NNODES);
  fill_k<<<(E+255)/256, 256, 0, stream>>>(srcp, dstp, curs, srcs, E);

  // ---- LSTM: layer 1 (h1 in-place over X0), then layer 2 ----
  const int NBL = (NNODES + 47) / 48;   // 209 blocks
  lstm_half<1><<<NBL, 512, 0, stream>>>(X0, wih0b, whh0b, bsum, nullptr);
  lstm_half<0><<<NBL, 512, 0, stream>>>(X0, wih1b, whh1b, bsum + GDIM, zf);

  // ---- GAT layers ----
  const bf16* zin = zf;
  bf16* zouts[2] = {z2, z3};
  const int NB64 = (NNODES + 63) / 64;   // 157 blocks
  for (int l=0; l<2; l++){
    gemm_bt<0><<<dim3(79,8), 256, 0, stream>>>(zin, wlrb[l], gblr + l*1024, xc, NNODES, 1024, HID);
    gat_onl<<<(NNODES+3)/4, 256, 0, stream>>>(offsb, srcs, xc, g_att[l], g_bias[l], agg);
    gemm_bt64<1><<<NB64, 256, 0, stream>>>(agg, pwb[l], g_pb[l], zouts[l], NNODES, GDIM);
    zin = zouts[l];
  }

  // ---- MLP out ----
  gemm_bt64<1><<<NB64, 256, 0, stream>>>(z3, mow0b, mob0, o0, NNODES, HID);
  mlp_final_k<<<(NNODES*24+255)/256, 256, 0, stream>>>(o0, mow1, mob1, (float*)d_out);
}

// Round 12
// 629.182 us; speedup vs baseline: 1.0831x; 1.0831x over previous
//
#include <hip/hip_runtime.h>
#include <hip/hip_bf16.h>

#define NNODES 10000
#define TLEN 24
#define INDIM 16
#define HID 128
#define GDIM 512   // 4*HID (LSTM gates) == HEADS*HID (GAT)

typedef __hip_bfloat16 bf16;
typedef short v8s __attribute__((ext_vector_type(8)));
typedef float v4f __attribute__((ext_vector_type(4)));

__device__ inline float u2f(unsigned u){ return __uint_as_float(u); }

__device__ inline void unpack8(uint4 v, float* f){
  f[0]=u2f(v.x<<16); f[1]=u2f(v.x&0xFFFF0000u);
  f[2]=u2f(v.y<<16); f[3]=u2f(v.y&0xFFFF0000u);
  f[4]=u2f(v.z<<16); f[5]=u2f(v.z&0xFFFF0000u);
  f[6]=u2f(v.w<<16); f[7]=u2f(v.w&0xFFFF0000u);
}

// fast device transcendentals (v_exp_f32 + v_rcp_f32; inf-safe)
__device__ inline float fsig(float x){
  return __builtin_amdgcn_rcpf(1.f + __expf(-x));
}
__device__ inline float ftanh(float x){
  float t = __expf(-2.f*fabsf(x));           // in (0,1], no overflow
  float r = (1.f - t) * __builtin_amdgcn_rcpf(1.f + t);
  return copysignf(r, x);
}

// ---------------------------------------------------------------------------
// Convert 11 f32 weight matrices (MFMA B-operands) to bf16.
// Order: wih0,whh0,wih1,whh1, wl0,wr0,pw0, wl1,wr1,pw1 (65536 ea), mow0 (16384).
// ---------------------------------------------------------------------------
__global__ __launch_bounds__(256) void conv_w_k(
    const float* s0, const float* s1, const float* s2, const float* s3,
    const float* s4, const float* s5, const float* s6, const float* s7,
    const float* s8, const float* s9, const float* s10, bf16* __restrict__ dst)
{
  int idx = blockIdx.x*256 + threadIdx.x;
  if (idx >= 671744) return;
  int c = idx >> 16;
  float v;
  if (c < 10){
    const float* srcs[10] = {s0,s1,s2,s3,s4,s5,s6,s7,s8,s9};
    v = srcs[c][idx & 0xFFFF];
  } else {
    v = s10[idx - 655360];
  }
  dst[idx] = __float2bfloat16(v);
}

// ---------------------------------------------------------------------------
// Prep: folded MLP-in weights (f32), presummed LSTM biases, concat GAT biases.
// ---------------------------------------------------------------------------
__global__ void prep_w_k(
    const float* __restrict__ miw0, const float* __restrict__ mib0,
    const float* __restrict__ miw1, const float* __restrict__ mib1,
    const float* __restrict__ bih0, const float* __restrict__ bhh0,
    const float* __restrict__ bih1, const float* __restrict__ bhh1,
    const float* __restrict__ bl0, const float* __restrict__ br0,
    const float* __restrict__ bl1, const float* __restrict__ br1,
    float* __restrict__ Wp, float* __restrict__ bp,
    float* __restrict__ bsum, float* __restrict__ gblr)
{
  int t = threadIdx.x;
  for (int idx = t; idx < HID*INDIM; idx += 256){
    int j = idx >> 4, d = idx & 15;
    float s = 0.f;
    for (int k=0;k<HID;k++) s += miw1[j*HID+k] * miw0[k*INDIM+d];
    Wp[idx] = s;
  }
  for (int j = t; j < HID; j += 256){
    float s = mib1[j];
    for (int k=0;k<HID;k++) s += miw1[j*HID+k] * mib0[k];
    bp[j] = s;
  }
  for (int i = t; i < GDIM; i += 256){
    bsum[i]        = bih0[i] + bhh0[i];
    bsum[GDIM + i] = bih1[i] + bhh1[i];
  }
  for (int i = t; i < GDIM; i += 256){
    gblr[i]          = bl0[i];
    gblr[GDIM + i]   = br0[i];
    gblr[1024 + i]   = bl1[i];
    gblr[1536 + i]   = br1[i];
  }
}

// ---------------------------------------------------------------------------
// MLP-in: 64-row x-tile in LDS, W row in registers. Grid 3750.
// ---------------------------------------------------------------------------
__global__ __launch_bounds__(256) void mlp_in_k(
    const float* __restrict__ x, const float* __restrict__ Wp,
    const float* __restrict__ bp, bf16* __restrict__ X0)
{
  __shared__ __align__(16) float xs[64*16];
  const int tid = threadIdx.x;
  const int m0 = blockIdx.x*64;
  {
    int row = tid >> 2, q = tid & 3;
    int m = m0 + row;
    int t = m / NNODES, n = m - t*NNODES;
    float4 v = *(const float4*)(x + ((size_t)n*TLEN + t)*INDIM + q*4);
    *(float4*)(xs + row*16 + q*4) = v;
  }
  const int j = tid & 127;
  const int half = tid >> 7;
  const float* wr = Wp + j*INDIM;
  float4 w0 = *(const float4*)(wr);
  float4 w1 = *(const float4*)(wr + 4);
  float4 w2 = *(const float4*)(wr + 8);
  float4 w3 = *(const float4*)(wr + 12);
  float bj = bp[j];
  __syncthreads();
  #pragma unroll 4
  for (int mi=0; mi<32; mi++){
    int row = mi*2 + half;
    const float* xr = xs + row*16;
    float4 a0 = *(const float4*)(xr);
    float4 a1 = *(const float4*)(xr + 4);
    float4 a2 = *(const float4*)(xr + 8);
    float4 a3 = *(const float4*)(xr + 12);
    float s = bj
      + a0.x*w0.x + a0.y*w0.y + a0.z*w0.z + a0.w*w0.w
      + a1.x*w1.x + a1.y*w1.y + a1.z*w1.z + a1.w*w1.w
      + a2.x*w2.x + a2.y*w2.y + a2.z*w2.z + a2.w*w2.w
      + a3.x*w3.x + a3.y*w3.y + a3.z*w3.z + a3.w*w3.w;
    s = s > 0.f ? s : 0.f;
    X0[(size_t)(m0+row)*HID + j] = __float2bfloat16(s);
  }
}

// ---------------------------------------------------------------------------
// LSTM, one layer, 24 steps. Register-resident weights, X prefetch (issued
// EARLY so the hh phase + epilogue hide its latency before the barrier's
// mandatory vmcnt drain — r11 taught us late prefetch puts the full HBM
// latency inside the barrier), fast transcendentals, double-buffered LDS h,
// rolled t-loop (I-cache resident body).
// ---------------------------------------------------------------------------
template<int WRITE_ALL>
__global__ __launch_bounds__(512, 2) void lstm_half(
    const bf16* __restrict__ Xin, const bf16* __restrict__ Wih,
    const bf16* __restrict__ Whh, const float* __restrict__ bias,
    bf16* __restrict__ out)
{
  __shared__ __align__(16) bf16 hsA[48*136];
  __shared__ __align__(16) bf16 hsB[48*136];
  const int tid = threadIdx.x;
  const int lane = tid & 63, w = tid >> 6;
  const int r16 = lane & 15, quad = lane >> 4;
  const int m0 = blockIdx.x*48;

  // weights -> registers (once)
  v8s wbi[4][4], wbh[4][4];
  #pragma unroll
  for (int g=0; g<4; g++)
    #pragma unroll
    for (int kc=0; kc<4; kc++){
      size_t o = (size_t)(g*HID + w*16 + r16)*HID + kc*32 + quad*8;
      wbi[g][kc] = *(const v8s*)(Wih + o);
      wbh[g][kc] = *(const v8s*)(Whh + o);
    }
  float bg[4];
  #pragma unroll
  for (int g=0; g<4; g++) bg[g] = bias[g*HID + w*16 + r16];

  // clamped A-row offsets
  size_t rowoff[3];
  #pragma unroll
  for (int mi=0; mi<3; mi++){
    int r = m0 + mi*16 + r16;
    rowoff[mi] = (size_t)(r < NNODES ? r : NNODES-1) * HID;
  }

  float c[12];
  #pragma unroll
  for (int i=0;i<12;i++) c[i] = 0.f;

  // zero both h buffers (t=0 reads hsB)
  for (int i = tid; i < 816; i += 512){
    *(uint4*)((char*)hsA + i*16) = make_uint4(0,0,0,0);
    *(uint4*)((char*)hsB + i*16) = make_uint4(0,0,0,0);
  }

  // preload X[0] fragments
  v8s ax[3][4];
  #pragma unroll
  for (int kc=0; kc<4; kc++)
    #pragma unroll
    for (int mi=0; mi<3; mi++)
      ax[mi][kc] = *(const v8s*)(Xin + rowoff[mi] + kc*32 + quad*8);

  __syncthreads();

  #pragma unroll 1
  for (int t=0; t<TLEN; t++){
    // h[t] -> buf[t&1]; h[t-1] in buf[(t-1)&1]; t=0 reads zeroed hsB
    bf16* hrd = (t & 1) ? hsA : hsB;
    bf16* hwr = (t & 1) ? hsB : hsA;

    v4f acc[3][4];
    #pragma unroll
    for (int mi=0;mi<3;mi++)
      #pragma unroll
      for (int g=0;g<4;g++) acc[mi][g] = (v4f)0.f;

    // ih from prefetched registers
    #pragma unroll
    for (int kc=0; kc<4; kc++)
      #pragma unroll
      for (int mi=0;mi<3;mi++)
        #pragma unroll
        for (int g=0;g<4;g++)
          acc[mi][g] = __builtin_amdgcn_mfma_f32_16x16x32_bf16(ax[mi][kc], wbi[g][kc], acc[mi][g], 0, 0, 0);

    // prefetch X[t+1] EARLY (clamped): hh phase + epilogue hide the latency
    // before the barrier's vmcnt drain
    {
      int tn = t+1 < TLEN ? t+1 : TLEN-1;
      const bf16* Xn = Xin + (size_t)tn*NNODES*HID;
      #pragma unroll
      for (int kc=0; kc<4; kc++)
        #pragma unroll
        for (int mi=0; mi<3; mi++)
          ax[mi][kc] = *(const v8s*)(Xn + rowoff[mi] + kc*32 + quad*8);
    }

    // hh from LDS h[t-1]
    #pragma unroll
    for (int kc=0; kc<4; kc++){
      v8s av[3];
      #pragma unroll
      for (int mi=0;mi<3;mi++)
        av[mi] = *(const v8s*)(hrd + (mi*16 + r16)*136 + kc*32 + quad*8);
      #pragma unroll
      for (int mi=0;mi<3;mi++)
        #pragma unroll
        for (int g=0;g<4;g++)
          acc[mi][g] = __builtin_amdgcn_mfma_f32_16x16x32_bf16(av[mi], wbh[g][kc], acc[mi][g], 0, 0, 0);
    }

    // epilogue writes h[t] into hwr (different buffer than hrd -> no WAR)
    #pragma unroll
    for (int mi=0;mi<3;mi++)
      #pragma unroll
      for (int r=0;r<4;r++){
        int lrow = mi*16 + quad*4 + r;
        float iv = acc[mi][0][r] + bg[0];
        float fv = acc[mi][1][r] + bg[1];
        float gv = acc[mi][2][r] + bg[2];
        float ov = acc[mi][3][r] + bg[3];
        float ig = fsig(iv), fg = fsig(fv);
        float gg = ftanh(gv), og = fsig(ov);
        int ci = mi*4 + r;
        float cn = fg*c[ci] + ig*gg;
        c[ci] = cn;
        hwr[lrow*136 + w*16 + r16] = __float2bfloat16(og*ftanh(cn));
      }
    __syncthreads();   // h[t] visible (single barrier per step)

    if (WRITE_ALL){
      bf16* dst = (bf16*)(Xin + (size_t)t*NNODES*HID);  // own rows only
      for (int i = tid; i < 768; i += 512){
        int row = i >> 4, c8 = (i & 15) * 8;
        if (m0 + row < NNODES)
          *(uint4*)(dst + (size_t)(m0+row)*HID + c8) = *(const uint4*)(hwr + row*136 + c8);
      }
    }
  }

  if (!WRITE_ALL){
    const bf16* hfin = ((TLEN-1) & 1) ? hsB : hsA;
    for (int i = tid; i < 768; i += 512){
      int row = i >> 4, c8 = (i & 15) * 8;
      if (m0 + row < NNODES)
        *(uint4*)(out + (size_t)(m0+row)*HID + c8) = *(const uint4*)(hfin + row*136 + c8);
    }
  }
}

// ---------------------------------------------------------------------------
// Generic bf16 GEMM: C[M,N] = act(A[M,K] @ B[N,K]^T + bias_f32[N]), bf16 out.
// 128x128 tile, 256 thr.
// ---------------------------------------------------------------------------
template<int ACT>
__global__ __launch_bounds__(256) void gemm_bt(
    const bf16* __restrict__ A, const bf16* __restrict__ B,
    const float* __restrict__ bias, bf16* __restrict__ C,
    int M, int N, int K)
{
  __shared__ __align__(16) bf16 As[128*40];
  __shared__ __align__(16) bf16 Bs[128*40];
  const int tid = threadIdx.x;
  const int m0 = blockIdx.x*128, n0 = blockIdx.y*128;
  const int lane = tid & 63, wave = tid >> 6;
  const int r16 = lane & 15, quad = lane >> 4;

  v4f acc[2][8];
  #pragma unroll
  for (int a=0;a<2;a++)
    #pragma unroll
    for (int b=0;b<8;b++) acc[a][b] = (v4f)0.f;

  for (int k0=0; k0<K; k0+=32){
    #pragma unroll
    for (int i=0;i<2;i++){
      int li = tid + i*256;
      int row = li >> 2, q4 = li & 3;
      uint4 va = make_uint4(0,0,0,0);
      int gm = m0 + row;
      if (gm < M) va = *(const uint4*)(A + (size_t)gm*K + k0 + q4*8);
      *(uint4*)(As + row*40 + q4*8) = va;
      uint4 vb = make_uint4(0,0,0,0);
      int gn = n0 + row;
      if (gn < N) vb = *(const uint4*)(B + (size_t)gn*K + k0 + q4*8);
      *(uint4*)(Bs + row*40 + q4*8) = vb;
    }
    __syncthreads();
    v8s av[2], bv[8];
    #pragma unroll
    for (int mi=0;mi<2;mi++)
      av[mi] = *(const v8s*)(As + (wave*32 + mi*16 + r16)*40 + quad*8);
    #pragma unroll
    for (int ni=0;ni<8;ni++)
      bv[ni] = *(const v8s*)(Bs + (ni*16 + r16)*40 + quad*8);
    #pragma unroll
    for (int mi=0;mi<2;mi++)
      #pragma unroll
      for (int ni=0;ni<8;ni++)
        acc[mi][ni] = __builtin_amdgcn_mfma_f32_16x16x32_bf16(av[mi], bv[ni], acc[mi][ni], 0, 0, 0);
    __syncthreads();
  }

  #pragma unroll
  for (int mi=0;mi<2;mi++){
    #pragma unroll
    for (int r=0;r<4;r++){
      int row = m0 + wave*32 + mi*16 + quad*4 + r;
      if (row >= M) continue;
      #pragma unroll
      for (int ni=0;ni<8;ni++){
        int col = n0 + ni*16 + r16;
        float v = acc[mi][ni][r] + bias[col];
        if (ACT == 1) v = v > 0.f ? v : 0.f;
        C[(size_t)row*N + col] = __float2bfloat16(v);
      }
    }
  }
}

// ---------------------------------------------------------------------------
// 64-row-tile GEMM for N=128 outputs (projection / mlp-out): 2x the blocks
// of the 128-tile for small-M work. Same K-order -> bit-identical results.
// ---------------------------------------------------------------------------
template<int ACT>
__global__ __launch_bounds__(256) void gemm_bt64(
    const bf16* __restrict__ A, const bf16* __restrict__ B,
    const float* __restrict__ bias, bf16* __restrict__ C,
    int M, int K)   // N == 128
{
  __shared__ __align__(16) bf16 As[64*40];
  __shared__ __align__(16) bf16 Bs[128*40];
  const int tid = threadIdx.x;
  const int m0 = blockIdx.x*64;
  const int lane = tid & 63, wave = tid >> 6;
  const int r16 = lane & 15, quad = lane >> 4;

  v4f acc[8];
  #pragma unroll
  for (int b=0;b<8;b++) acc[b] = (v4f)0.f;

  for (int k0=0; k0<K; k0+=32){
    {
      int row = tid >> 2, q4 = tid & 3;
      uint4 va = make_uint4(0,0,0,0);
      int gm = m0 + row;
      if (gm < M) va = *(const uint4*)(A + (size_t)gm*K + k0 + q4*8);
      *(uint4*)(As + row*40 + q4*8) = va;
    }
    #pragma unroll
    for (int i=0;i<2;i++){
      int li = tid + i*256;
      int row = li >> 2, q4 = li & 3;
      uint4 vb = *(const uint4*)(B + (size_t)row*K + k0 + q4*8);
      *(uint4*)(Bs + row*40 + q4*8) = vb;
    }
    __syncthreads();
    v8s av, bv[8];
    av = *(const v8s*)(As + (wave*16 + r16)*40 + quad*8);
    #pragma unroll
    for (int ni=0;ni<8;ni++)
      bv[ni] = *(const v8s*)(Bs + (ni*16 + r16)*40 + quad*8);
    #pragma unroll
    for (int ni=0;ni<8;ni++)
      acc[ni] = __builtin_amdgcn_mfma_f32_16x16x32_bf16(av, bv[ni], acc[ni], 0, 0, 0);
    __syncthreads();
  }

  #pragma unroll
  for (int r=0;r<4;r++){
    int row = m0 + wave*16 + quad*4 + r;
    if (row >= M) continue;
    #pragma unroll
    for (int ni=0;ni<8;ni++){
      int col = ni*16 + r16;
      float v = acc[ni][r] + bias[col];
      if (ACT == 1) v = v > 0.f ? v : 0.f;
      C[(size_t)row*HID + col] = __float2bfloat16(v);
    }
  }
}

// ---------------------------------------------------------------------------
// CSR build (payload = resolved src id)
// ---------------------------------------------------------------------------
__global__ void deg_count_k(const int* __restrict__ dst, int* __restrict__ deg, int E){
  int e = blockIdx.x*256 + threadIdx.x;
  if (e < E){
    unsigned d = (unsigned)dst[e];
    if (d < (unsigned)NNODES) atomicAdd(&deg[d], 1);
  }
}

__global__ void scan_k(const int* __restrict__ deg, int* __restrict__ offs,
                       int* __restrict__ cursor, int n)
{
  __shared__ int part[256];
  __shared__ int base[256];
  int t = threadIdx.x;
  int lo = t*40, hi = lo+40;
  if (lo > n) lo = n;
  if (hi > n) hi = n;
  int s = 0;
  for (int i=lo;i<hi;i++) s += deg[i];
  part[t] = s;
  __syncthreads();
  if (t == 0){
    int run=0;
    for (int i=0;i<256;i++){ base[i]=run; run+=part[i]; }
    offs[n] = run;
  }
  __syncthreads();
  int run = base[t];
  for (int i=lo;i<hi;i++){ offs[i]=run; cursor[i]=run; run += deg[i]; }
}

__global__ void fill_k(const int* __restrict__ src, const int* __restrict__ dst,
                       int* __restrict__ cursor, int* __restrict__ srcs, int E){
  int e = blockIdx.x*256 + threadIdx.x;
  if (e < E){
    unsigned d = (unsigned)dst[e];
    if (d < (unsigned)NNODES){
      int p = atomicAdd(&cursor[d], 1);
      unsigned s = (unsigned)src[e];
      srcs[p] = (s < (unsigned)NNODES) ? (int)s : 0;
    }
  }
}

// ---------------------------------------------------------------------------
// GATv2 online-softmax fused score+aggregate. 1 wave/dst node.
// ---------------------------------------------------------------------------
__global__ __launch_bounds__(256) void gat_onl(
    const int* __restrict__ offs, const int* __restrict__ srcs,
    const bf16* __restrict__ xc, const float* __restrict__ att,
    const float* __restrict__ gbias, bf16* __restrict__ agg)
{
  int d = blockIdx.x*4 + (threadIdx.x >> 6);
  if (d >= NNODES) return;
  int lane = threadIdx.x & 63;
  float fr[8];
  unpack8(*(const uint4*)(xc + (size_t)d*1024 + 512 + lane*8), fr);
  float4 a0 = *(const float4*)(att + lane*8);
  float4 a1 = *(const float4*)(att + lane*8 + 4);
  float fa[8] = {a0.x,a0.y,a0.z,a0.w,a1.x,a1.y,a1.z,a1.w};
  int i0 = offs[d], i1 = offs[d+1];

  float m = -3.4e38f, den = 0.f;
  float acc[8] = {0,0,0,0,0,0,0,0};
  for (int i=i0; i<i1; i++){
    int s = srcs[i];
    float fl[8];
    unpack8(*(const uint4*)(xc + (size_t)s*1024 + lane*8), fl);
    float p = 0.f;
    #pragma unroll
    for (int q=0;q<8;q++){
      float v = fl[q] + fr[q];
      v = v > 0.f ? v : 0.2f*v;
      p += v*fa[q];
    }
    p += __shfl_xor(p, 1); p += __shfl_xor(p, 2);
    p += __shfl_xor(p, 4); p += __shfl_xor(p, 8);
    float mn = fmaxf(m, p);
    float corr = __expf(m - mn);
    float w = __expf(p - mn);
    den = den*corr + w;
    #pragma unroll
    for (int q=0;q<8;q++) acc[q] = acc[q]*corr + w*fl[q];
    m = mn;
  }
  float r = 1.f/(den + 1e-16f);
  float4 b0 = *(const float4*)(gbias + lane*8);
  float4 b1 = *(const float4*)(gbias + lane*8 + 4);
  float fb[8] = {b0.x,b0.y,b0.z,b0.w,b1.x,b1.y,b1.z,b1.w};
  #pragma unroll
  for (int q=0;q<8;q++)
    agg[(size_t)d*GDIM + lane*8 + q] = __float2bfloat16(acc[q]*r + fb[q]);
}

// ---------------------------------------------------------------------------
// Final linear (N=24): f32 weights, f32 out.
// ---------------------------------------------------------------------------
__global__ __launch_bounds__(256) void mlp_final_k(
    const bf16* __restrict__ a, const float* __restrict__ w,
    const float* __restrict__ b, float* __restrict__ out)
{
  int g = blockIdx.x*256 + threadIdx.x;
  if (g >= NNODES*24) return;
  int j = g % 24;
  int row = g / 24;
  const bf16* ar = a + (size_t)row*HID;
  const float* wr = w + (size_t)j*HID;
  float s = b[j];
  for (int k=0;k<HID;k+=8){
    float fa[8];
    unpack8(*(const uint4*)(ar+k), fa);
    float4 w0 = *(const float4*)(wr + k);
    float4 w1 = *(const float4*)(wr + k + 4);
    s += fa[0]*w0.x + fa[1]*w0.y + fa[2]*w0.z + fa[3]*w0.w
       + fa[4]*w1.x + fa[5]*w1.y + fa[6]*w1.z + fa[7]*w1.w;
  }
  out[g] = s;
}

// ---------------------------------------------------------------------------

extern "C" void kernel_launch(void* const* d_in, const int* in_sizes, int n_in,
                              void* d_out, int out_size, void* d_ws, size_t ws_size,
                              hipStream_t stream)
{
  const float* x   = (const float*)d_in[0];
  const int*   ei  = (const int*)d_in[1];
  const int E = in_sizes[1] / 2;
  const int* srcp = ei;
  const int* dstp = ei + E;

  const float* miw0 = (const float*)d_in[2];
  const float* mib0 = (const float*)d_in[3];
  const float* miw1 = (const float*)d_in[4];
  const float* mib1 = (const float*)d_in[5];
  const float* wih0 = (const float*)d_in[6];
  const float* whh0 = (const float*)d_in[7];
  const float* bih0 = (const float*)d_in[8];
  const float* bhh0 = (const float*)d_in[9];
  const float* wih1 = (const float*)d_in[10];
  const float* whh1 = (const float*)d_in[11];
  const float* bih1 = (const float*)d_in[12];
  const float* bhh1 = (const float*)d_in[13];
  const float* g_wl[2]   = {(const float*)d_in[14], (const float*)d_in[22]};
  const float* g_bl[2]   = {(const float*)d_in[15], (const float*)d_in[23]};
  const float* g_wr[2]   = {(const float*)d_in[16], (const float*)d_in[24]};
  const float* g_br[2]   = {(const float*)d_in[17], (const float*)d_in[25]};
  const float* g_att[2]  = {(const float*)d_in[18], (const float*)d_in[26]};
  const float* g_bias[2] = {(const float*)d_in[19], (const float*)d_in[27]};
  const float* g_pw[2]   = {(const float*)d_in[20], (const float*)d_in[28]};
  const float* g_pb[2]   = {(const float*)d_in[21], (const float*)d_in[29]};
  const float* mow0 = (const float*)d_in[30];
  const float* mob0 = (const float*)d_in[31];
  const float* mow1 = (const float*)d_in[32];
  const float* mob1 = (const float*)d_in[33];
  (void)n_in; (void)out_size; (void)ws_size;

  // ---- workspace layout ----
  char* base = (char*)d_ws;
  size_t off = 0;
  auto carve = [&](size_t n)->char*{
    char* p = base + off;
    off = (off + n + 255) & ~(size_t)255;
    return p;
  };
  char*  X0r = carve((size_t)TLEN*NNODES*HID*2);   // 61,440,000
  bf16*  zf  = (bf16*)carve((size_t)NNODES*HID*2);
  float* Wp  = (float*)carve(HID*INDIM*4);
  float* bp  = (float*)carve(HID*4);
  float* bsum= (float*)carve(2*GDIM*4);
  float* gblr= (float*)carve(2*1024*4);
  bf16*  wbf = (bf16*)carve((size_t)671744*2);
  int*   offsb = (int*)carve((size_t)(NNODES+1)*4);
  int*   curs  = (int*)carve((size_t)NNODES*4);
  int*   srcs  = (int*)carve((size_t)E*4);
  int*   deg   = (int*)carve((size_t)NNODES*4);
  bf16*  agg   = (bf16*)carve((size_t)NNODES*GDIM*2);

  // wbf sub-pointers (conv_w_k chunk order)
  const bf16* wih0b = wbf + 0;
  const bf16* whh0b = wbf + 65536;
  const bf16* wih1b = wbf + 131072;
  const bf16* whh1b = wbf + 196608;
  const bf16* wlr0b = wbf + 262144;   // wl0|wr0 contiguous [1024,128]
  const bf16* pw0b  = wbf + 393216;
  const bf16* wlr1b = wbf + 458752;   // wl1|wr1 contiguous
  const bf16* pw1b  = wbf + 589824;
  const bf16* mow0b = wbf + 655360;
  const bf16* wlrb[2] = {wlr0b, wlr1b};
  const bf16* pwb[2]  = {pw0b, pw1b};

  // X0 region aliases (holds X0, then h1 in-place, dead after LSTM)
  bf16* X0 = (bf16*)X0r;
  bf16* xc = (bf16*)X0r;                      // [10000,1024] = xl|xr
  bf16* z2 = (bf16*)(X0r + 20480000);
  bf16* z3 = (bf16*)(X0r + 23040000);
  bf16* o0 = (bf16*)(X0r + 25600000);

  // ---- prep ----
  conv_w_k<<<2624, 256, 0, stream>>>(wih0, whh0, wih1, whh1,
                                     g_wl[0], g_wr[0], g_pw[0],
                                     g_wl[1], g_wr[1], g_pw[1], mow0, wbf);
  prep_w_k<<<1, 256, 0, stream>>>(miw0, mib0, miw1, mib1,
                                  bih0, bhh0, bih1, bhh1,
                                  g_bl[0], g_br[0], g_bl[1], g_br[1],
                                  Wp, bp, bsum, gblr);
  hipMemsetAsync(deg, 0, (size_t)NNODES*4, stream);

  // ---- MLP in ----
  mlp_in_k<<<(TLEN*NNODES)/64, 256, 0, stream>>>(x, Wp, bp, X0);

  // ---- CSR build ----
  deg_count_k<<<(E+255)/256, 256, 0, stream>>>(dstp, deg, E);
  scan_k<<<1, 256, 0, stream>>>(deg, offsb, curs, NNODES);
  fill_k<<<(E+255)/256, 256, 0, stream>>>(srcp, dstp, curs, srcs, E);

  // ---- LSTM: layer 1 (h1 in-place over X0), then layer 2 ----
  const int NBL = (NNODES + 47) / 48;   // 209 blocks
  lstm_half<1><<<NBL, 512, 0, stream>>>(X0, wih0b, whh0b, bsum, nullptr);
  lstm_half<0><<<NBL, 512, 0, stream>>>(X0, wih1b, whh1b, bsum + GDIM, zf);

  // ---- GAT layers ----
  const bf16* zin = zf;
  bf16* zouts[2] = {z2, z3};
  const int NB64 = (NNODES + 63) / 64;   // 157 blocks
  for (int l=0; l<2; l++){
    gemm_bt<0><<<dim3(79,8), 256, 0, stream>>>(zin, wlrb[l], gblr + l*1024, xc, NNODES, 1024, HID);
    gat_onl<<<(NNODES+3)/4, 256, 0, stream>>>(offsb, srcs, xc, g_att[l], g_bias[l], agg);
    gemm_bt64<1><<<NB64, 256, 0, stream>>>(agg, pwb[l], g_pb[l], zouts[l], NNODES, GDIM);
    zin = zouts[l];
  }

  // ---- MLP out ----
  gemm_bt64<1><<<NB64, 256, 0, stream>>>(z3, mow0b, mob0, o0, NNODES, HID);
  mlp_final_k<<<(NNODES*24+255)/256, 256, 0, stream>>>(o0, mow1, mob1, (float*)d_out);
}

// Round 13
// 610.138 us; speedup vs baseline: 1.1169x; 1.0312x over previous
//
#include <hip/hip_runtime.h>
#include <hip/hip_bf16.h>

#define NNODES 10000
#define TLEN 24
#define INDIM 16
#define HID 128
#define GDIM 512   // 4*HID (LSTM gates) == HEADS*HID (GAT)

typedef __hip_bfloat16 bf16;
typedef short v8s __attribute__((ext_vector_type(8)));
typedef float v4f __attribute__((ext_vector_type(4)));

__device__ inline float u2f(unsigned u){ return __uint_as_float(u); }

__device__ inline void unpack8(uint4 v, float* f){
  f[0]=u2f(v.x<<16); f[1]=u2f(v.x&0xFFFF0000u);
  f[2]=u2f(v.y<<16); f[3]=u2f(v.y&0xFFFF0000u);
  f[4]=u2f(v.z<<16); f[5]=u2f(v.z&0xFFFF0000u);
  f[6]=u2f(v.w<<16); f[7]=u2f(v.w&0xFFFF0000u);
}

// fast device transcendentals (v_exp_f32 + v_rcp_f32; inf-safe)
__device__ inline float fsig(float x){
  return __builtin_amdgcn_rcpf(1.f + __expf(-x));
}
__device__ inline float ftanh(float x){
  float t = __expf(-2.f*fabsf(x));           // in (0,1], no overflow
  float r = (1.f - t) * __builtin_amdgcn_rcpf(1.f + t);
  return copysignf(r, x);
}

// ---------------------------------------------------------------------------
// Convert 11 f32 weight matrices (MFMA B-operands) to bf16.
// Order: wih0,whh0,wih1,whh1, wl0,wr0,pw0, wl1,wr1,pw1 (65536 ea), mow0 (16384).
// ---------------------------------------------------------------------------
__global__ __launch_bounds__(256) void conv_w_k(
    const float* s0, const float* s1, const float* s2, const float* s3,
    const float* s4, const float* s5, const float* s6, const float* s7,
    const float* s8, const float* s9, const float* s10, bf16* __restrict__ dst)
{
  int idx = blockIdx.x*256 + threadIdx.x;
  if (idx >= 671744) return;
  int c = idx >> 16;
  float v;
  if (c < 10){
    const float* srcs[10] = {s0,s1,s2,s3,s4,s5,s6,s7,s8,s9};
    v = srcs[c][idx & 0xFFFF];
  } else {
    v = s10[idx - 655360];
  }
  dst[idx] = __float2bfloat16(v);
}

// ---------------------------------------------------------------------------
// Prep: folded MLP-in weights (f32), presummed LSTM biases, concat GAT biases.
// ---------------------------------------------------------------------------
__global__ void prep_w_k(
    const float* __restrict__ miw0, const float* __restrict__ mib0,
    const float* __restrict__ miw1, const float* __restrict__ mib1,
    const float* __restrict__ bih0, const float* __restrict__ bhh0,
    const float* __restrict__ bih1, const float* __restrict__ bhh1,
    const float* __restrict__ bl0, const float* __restrict__ br0,
    const float* __restrict__ bl1, const float* __restrict__ br1,
    float* __restrict__ Wp, float* __restrict__ bp,
    float* __restrict__ bsum, float* __restrict__ gblr)
{
  int t = threadIdx.x;
  for (int idx = t; idx < HID*INDIM; idx += 256){
    int j = idx >> 4, d = idx & 15;
    float s = 0.f;
    for (int k=0;k<HID;k++) s += miw1[j*HID+k] * miw0[k*INDIM+d];
    Wp[idx] = s;
  }
  for (int j = t; j < HID; j += 256){
    float s = mib1[j];
    for (int k=0;k<HID;k++) s += miw1[j*HID+k] * mib0[k];
    bp[j] = s;
  }
  for (int i = t; i < GDIM; i += 256){
    bsum[i]        = bih0[i] + bhh0[i];
    bsum[GDIM + i] = bih1[i] + bhh1[i];
  }
  for (int i = t; i < GDIM; i += 256){
    gblr[i]          = bl0[i];
    gblr[GDIM + i]   = br0[i];
    gblr[1024 + i]   = bl1[i];
    gblr[1536 + i]   = br1[i];
  }
}

// ---------------------------------------------------------------------------
// MLP-in: 64-row x-tile in LDS, W row in registers. Grid 3750.
// ---------------------------------------------------------------------------
__global__ __launch_bounds__(256) void mlp_in_k(
    const float* __restrict__ x, const float* __restrict__ Wp,
    const float* __restrict__ bp, bf16* __restrict__ X0)
{
  __shared__ __align__(16) float xs[64*16];
  const int tid = threadIdx.x;
  const int m0 = blockIdx.x*64;
  {
    int row = tid >> 2, q = tid & 3;
    int m = m0 + row;
    int t = m / NNODES, n = m - t*NNODES;
    float4 v = *(const float4*)(x + ((size_t)n*TLEN + t)*INDIM + q*4);
    *(float4*)(xs + row*16 + q*4) = v;
  }
  const int j = tid & 127;
  const int half = tid >> 7;
  const float* wr = Wp + j*INDIM;
  float4 w0 = *(const float4*)(wr);
  float4 w1 = *(const float4*)(wr + 4);
  float4 w2 = *(const float4*)(wr + 8);
  float4 w3 = *(const float4*)(wr + 12);
  float bj = bp[j];
  __syncthreads();
  #pragma unroll 4
  for (int mi=0; mi<32; mi++){
    int row = mi*2 + half;
    const float* xr = xs + row*16;
    float4 a0 = *(const float4*)(xr);
    float4 a1 = *(const float4*)(xr + 4);
    float4 a2 = *(const float4*)(xr + 8);
    float4 a3 = *(const float4*)(xr + 12);
    float s = bj
      + a0.x*w0.x + a0.y*w0.y + a0.z*w0.z + a0.w*w0.w
      + a1.x*w1.x + a1.y*w1.y + a1.z*w1.z + a1.w*w1.w
      + a2.x*w2.x + a2.y*w2.y + a2.z*w2.z + a2.w*w2.w
      + a3.x*w3.x + a3.y*w3.y + a3.z*w3.z + a3.w*w3.w;
    s = s > 0.f ? s : 0.f;
    X0[(size_t)(m0+row)*HID + j] = __float2bfloat16(s);
  }
}

// ---------------------------------------------------------------------------
// LSTM, one layer, 24 steps. M=16 rows/block -> 625 blocks so ~2 blocks/CU
// co-reside (VGPR 128 -> 4 waves/SIMD): co-resident blocks interleave their
// barrier stalls + trans epilogues (single-block CUs can't). Same proven
// structure: register weights, EARLY X prefetch, dbuf LDS h, rolled t-loop.
// ---------------------------------------------------------------------------
template<int WRITE_ALL>
__global__ __launch_bounds__(512) void lstm_half(
    const bf16* __restrict__ Xin, const bf16* __restrict__ Wih,
    const bf16* __restrict__ Whh, const float* __restrict__ bias,
    bf16* __restrict__ out)
{
  __shared__ __align__(16) bf16 hsA[16*136];
  __shared__ __align__(16) bf16 hsB[16*136];
  const int tid = threadIdx.x;
  const int lane = tid & 63, w = tid >> 6;
  const int r16 = lane & 15, quad = lane >> 4;
  const int m0 = blockIdx.x*16;   // 625*16 == 10000 exactly

  // weights -> registers (once): wave w owns cols [16w,16w+16) of all 4 gates
  v8s wbi[4][4], wbh[4][4];
  #pragma unroll
  for (int g=0; g<4; g++)
    #pragma unroll
    for (int kc=0; kc<4; kc++){
      size_t o = (size_t)(g*HID + w*16 + r16)*HID + kc*32 + quad*8;
      wbi[g][kc] = *(const v8s*)(Wih + o);
      wbh[g][kc] = *(const v8s*)(Whh + o);
    }
  float bg[4];
  #pragma unroll
  for (int g=0; g<4; g++) bg[g] = bias[g*HID + w*16 + r16];

  const size_t rowoff = (size_t)(m0 + r16) * HID;

  float c[4];
  #pragma unroll
  for (int i=0;i<4;i++) c[i] = 0.f;

  // zero both h buffers (t=0 reads hsB); 272 uint4 each
  for (int i = tid; i < 272; i += 512){
    *(uint4*)((char*)hsA + i*16) = make_uint4(0,0,0,0);
    *(uint4*)((char*)hsB + i*16) = make_uint4(0,0,0,0);
  }

  // preload X[0] fragments
  v8s ax[4];
  #pragma unroll
  for (int kc=0; kc<4; kc++)
    ax[kc] = *(const v8s*)(Xin + rowoff + kc*32 + quad*8);

  __syncthreads();

  #pragma unroll 1
  for (int t=0; t<TLEN; t++){
    bf16* hrd = (t & 1) ? hsA : hsB;
    bf16* hwr = (t & 1) ? hsB : hsA;

    v4f acc[4];
    #pragma unroll
    for (int g=0;g<4;g++) acc[g] = (v4f)0.f;

    // ih from prefetched registers
    #pragma unroll
    for (int kc=0; kc<4; kc++)
      #pragma unroll
      for (int g=0;g<4;g++)
        acc[g] = __builtin_amdgcn_mfma_f32_16x16x32_bf16(ax[kc], wbi[g][kc], acc[g], 0, 0, 0);

    // prefetch X[t+1] EARLY: hh + epilogue hide latency before barrier drain
    {
      int tn = t+1 < TLEN ? t+1 : TLEN-1;
      const bf16* Xn = Xin + (size_t)tn*NNODES*HID;
      #pragma unroll
      for (int kc=0; kc<4; kc++)
        ax[kc] = *(const v8s*)(Xn + rowoff + kc*32 + quad*8);
    }

    // hh from LDS h[t-1]
    #pragma unroll
    for (int kc=0; kc<4; kc++){
      v8s av = *(const v8s*)(hrd + r16*136 + kc*32 + quad*8);
      #pragma unroll
      for (int g=0;g<4;g++)
        acc[g] = __builtin_amdgcn_mfma_f32_16x16x32_bf16(av, wbh[g][kc], acc[g], 0, 0, 0);
    }

    // epilogue: h[t] -> hwr (different buffer than hrd)
    #pragma unroll
    for (int r=0;r<4;r++){
      int lrow = quad*4 + r;
      float iv = acc[0][r] + bg[0];
      float fv = acc[1][r] + bg[1];
      float gv = acc[2][r] + bg[2];
      float ov = acc[3][r] + bg[3];
      float ig = fsig(iv), fg = fsig(fv);
      float gg = ftanh(gv), og = fsig(ov);
      float cn = fg*c[r] + ig*gg;
      c[r] = cn;
      hwr[lrow*136 + w*16 + r16] = __float2bfloat16(og*ftanh(cn));
    }
    __syncthreads();   // publish h[t]

    if (WRITE_ALL){
      bf16* dst = (bf16*)(Xin + (size_t)t*NNODES*HID);  // own rows only
      for (int i = tid; i < 256; i += 512){
        int row = i >> 4, c8 = (i & 15) * 8;
        *(uint4*)(dst + (size_t)(m0+row)*HID + c8) = *(const uint4*)(hwr + row*136 + c8);
      }
    }
  }

  if (!WRITE_ALL){
    const bf16* hfin = ((TLEN-1) & 1) ? hsB : hsA;
    for (int i = tid; i < 256; i += 512){
      int row = i >> 4, c8 = (i & 15) * 8;
      *(uint4*)(out + (size_t)(m0+row)*HID + c8) = *(const uint4*)(hfin + row*136 + c8);
    }
  }
}

// ---------------------------------------------------------------------------
// Generic bf16 GEMM: C[M,N] = act(A[M,K] @ B[N,K]^T + bias_f32[N]), bf16 out.
// 128x128 tile, 256 thr.
// ---------------------------------------------------------------------------
template<int ACT>
__global__ __launch_bounds__(256) void gemm_bt(
    const bf16* __restrict__ A, const bf16* __restrict__ B,
    const float* __restrict__ bias, bf16* __restrict__ C,
    int M, int N, int K)
{
  __shared__ __align__(16) bf16 As[128*40];
  __shared__ __align__(16) bf16 Bs[128*40];
  const int tid = threadIdx.x;
  const int m0 = blockIdx.x*128, n0 = blockIdx.y*128;
  const int lane = tid & 63, wave = tid >> 6;
  const int r16 = lane & 15, quad = lane >> 4;

  v4f acc[2][8];
  #pragma unroll
  for (int a=0;a<2;a++)
    #pragma unroll
    for (int b=0;b<8;b++) acc[a][b] = (v4f)0.f;

  for (int k0=0; k0<K; k0+=32){
    #pragma unroll
    for (int i=0;i<2;i++){
      int li = tid + i*256;
      int row = li >> 2, q4 = li & 3;
      uint4 va = make_uint4(0,0,0,0);
      int gm = m0 + row;
      if (gm < M) va = *(const uint4*)(A + (size_t)gm*K + k0 + q4*8);
      *(uint4*)(As + row*40 + q4*8) = va;
      uint4 vb = make_uint4(0,0,0,0);
      int gn = n0 + row;
      if (gn < N) vb = *(const uint4*)(B + (size_t)gn*K + k0 + q4*8);
      *(uint4*)(Bs + row*40 + q4*8) = vb;
    }
    __syncthreads();
    v8s av[2], bv[8];
    #pragma unroll
    for (int mi=0;mi<2;mi++)
      av[mi] = *(const v8s*)(As + (wave*32 + mi*16 + r16)*40 + quad*8);
    #pragma unroll
    for (int ni=0;ni<8;ni++)
      bv[ni] = *(const v8s*)(Bs + (ni*16 + r16)*40 + quad*8);
    #pragma unroll
    for (int mi=0;mi<2;mi++)
      #pragma unroll
      for (int ni=0;ni<8;ni++)
        acc[mi][ni] = __builtin_amdgcn_mfma_f32_16x16x32_bf16(av[mi], bv[ni], acc[mi][ni], 0, 0, 0);
    __syncthreads();
  }

  #pragma unroll
  for (int mi=0;mi<2;mi++){
    #pragma unroll
    for (int r=0;r<4;r++){
      int row = m0 + wave*32 + mi*16 + quad*4 + r;
      if (row >= M) continue;
      #pragma unroll
      for (int ni=0;ni<8;ni++){
        int col = n0 + ni*16 + r16;
        float v = acc[mi][ni][r] + bias[col];
        if (ACT == 1) v = v > 0.f ? v : 0.f;
        C[(size_t)row*N + col] = __float2bfloat16(v);
      }
    }
  }
}

// ---------------------------------------------------------------------------
// 64-row-tile GEMM for N=128 outputs (projection / mlp-out).
// ---------------------------------------------------------------------------
template<int ACT>
__global__ __launch_bounds__(256) void gemm_bt64(
    const bf16* __restrict__ A, const bf16* __restrict__ B,
    const float* __restrict__ bias, bf16* __restrict__ C,
    int M, int K)   // N == 128
{
  __shared__ __align__(16) bf16 As[64*40];
  __shared__ __align__(16) bf16 Bs[128*40];
  const int tid = threadIdx.x;
  const int m0 = blockIdx.x*64;
  const int lane = tid & 63, wave = tid >> 6;
  const int r16 = lane & 15, quad = lane >> 4;

  v4f acc[8];
  #pragma unroll
  for (int b=0;b<8;b++) acc[b] = (v4f)0.f;

  for (int k0=0; k0<K; k0+=32){
    {
      int row = tid >> 2, q4 = tid & 3;
      uint4 va = make_uint4(0,0,0,0);
      int gm = m0 + row;
      if (gm < M) va = *(const uint4*)(A + (size_t)gm*K + k0 + q4*8);
      *(uint4*)(As + row*40 + q4*8) = va;
    }
    #pragma unroll
    for (int i=0;i<2;i++){
      int li = tid + i*256;
      int row = li >> 2, q4 = li & 3;
      uint4 vb = *(const uint4*)(B + (size_t)row*K + k0 + q4*8);
      *(uint4*)(Bs + row*40 + q4*8) = vb;
    }
    __syncthreads();
    v8s av, bv[8];
    av = *(const v8s*)(As + (wave*16 + r16)*40 + quad*8);
    #pragma unroll
    for (int ni=0;ni<8;ni++)
      bv[ni] = *(const v8s*)(Bs + (ni*16 + r16)*40 + quad*8);
    #pragma unroll
    for (int ni=0;ni<8;ni++)
      acc[ni] = __builtin_amdgcn_mfma_f32_16x16x32_bf16(av, bv[ni], acc[ni], 0, 0, 0);
    __syncthreads();
  }

  #pragma unroll
  for (int r=0;r<4;r++){
    int row = m0 + wave*16 + quad*4 + r;
    if (row >= M) continue;
    #pragma unroll
    for (int ni=0;ni<8;ni++){
      int col = ni*16 + r16;
      float v = acc[ni][r] + bias[col];
      if (ACT == 1) v = v > 0.f ? v : 0.f;
      C[(size_t)row*HID + col] = __float2bfloat16(v);
    }
  }
}

// ---------------------------------------------------------------------------
// CSR build (payload = resolved src id)
// ---------------------------------------------------------------------------
__global__ void deg_count_k(const int* __restrict__ dst, int* __restrict__ deg, int E){
  int e = blockIdx.x*256 + threadIdx.x;
  if (e < E){
    unsigned d = (unsigned)dst[e];
    if (d < (unsigned)NNODES) atomicAdd(&deg[d], 1);
  }
}

__global__ void scan_k(const int* __restrict__ deg, int* __restrict__ offs,
                       int* __restrict__ cursor, int n)
{
  __shared__ int part[256];
  __shared__ int base[256];
  int t = threadIdx.x;
  int lo = t*40, hi = lo+40;
  if (lo > n) lo = n;
  if (hi > n) hi = n;
  int s = 0;
  for (int i=lo;i<hi;i++) s += deg[i];
  part[t] = s;
  __syncthreads();
  if (t == 0){
    int run=0;
    for (int i=0;i<256;i++){ base[i]=run; run+=part[i]; }
    offs[n] = run;
  }
  __syncthreads();
  int run = base[t];
  for (int i=lo;i<hi;i++){ offs[i]=run; cursor[i]=run; run += deg[i]; }
}

__global__ void fill_k(const int* __restrict__ src, const int* __restrict__ dst,
                       int* __restrict__ cursor, int* __restrict__ srcs, int E){
  int e = blockIdx.x*256 + threadIdx.x;
  if (e < E){
    unsigned d = (unsigned)dst[e];
    if (d < (unsigned)NNODES){
      int p = atomicAdd(&cursor[d], 1);
      unsigned s = (unsigned)src[e];
      srcs[p] = (s < (unsigned)NNODES) ? (int)s : 0;
    }
  }
}

// ---------------------------------------------------------------------------
// GATv2 online-softmax fused score+aggregate. 1 wave/dst node.
// ---------------------------------------------------------------------------
__global__ __launch_bounds__(256) void gat_onl(
    const int* __restrict__ offs, const int* __restrict__ srcs,
    const bf16* __restrict__ xc, const float* __restrict__ att,
    const float* __restrict__ gbias, bf16* __restrict__ agg)
{
  int d = blockIdx.x*4 + (threadIdx.x >> 6);
  if (d >= NNODES) return;
  int lane = threadIdx.x & 63;
  float fr[8];
  unpack8(*(const uint4*)(xc + (size_t)d*1024 + 512 + lane*8), fr);
  float4 a0 = *(const float4*)(att + lane*8);
  float4 a1 = *(const float4*)(att + lane*8 + 4);
  float fa[8] = {a0.x,a0.y,a0.z,a0.w,a1.x,a1.y,a1.z,a1.w};
  int i0 = offs[d], i1 = offs[d+1];

  float m = -3.4e38f, den = 0.f;
  float acc[8] = {0,0,0,0,0,0,0,0};
  for (int i=i0; i<i1; i++){
    int s = srcs[i];
    float fl[8];
    unpack8(*(const uint4*)(xc + (size_t)s*1024 + lane*8), fl);
    float p = 0.f;
    #pragma unroll
    for (int q=0;q<8;q++){
      float v = fl[q] + fr[q];
      v = v > 0.f ? v : 0.2f*v;
      p += v*fa[q];
    }
    p += __shfl_xor(p, 1); p += __shfl_xor(p, 2);
    p += __shfl_xor(p, 4); p += __shfl_xor(p, 8);
    float mn = fmaxf(m, p);
    float corr = __expf(m - mn);
    float w = __expf(p - mn);
    den = den*corr + w;
    #pragma unroll
    for (int q=0;q<8;q++) acc[q] = acc[q]*corr + w*fl[q];
    m = mn;
  }
  float r = 1.f/(den + 1e-16f);
  float4 b0 = *(const float4*)(gbias + lane*8);
  float4 b1 = *(const float4*)(gbias + lane*8 + 4);
  float fb[8] = {b0.x,b0.y,b0.z,b0.w,b1.x,b1.y,b1.z,b1.w};
  #pragma unroll
  for (int q=0;q<8;q++)
    agg[(size_t)d*GDIM + lane*8 + q] = __float2bfloat16(acc[q]*r + fb[q]);
}

// ---------------------------------------------------------------------------
// Final linear (N=24): f32 weights, f32 out.
// ---------------------------------------------------------------------------
__global__ __launch_bounds__(256) void mlp_final_k(
    const bf16* __restrict__ a, const float* __restrict__ w,
    const float* __restrict__ b, float* __restrict__ out)
{
  int g = blockIdx.x*256 + threadIdx.x;
  if (g >= NNODES*24) return;
  int j = g % 24;
  int row = g / 24;
  const bf16* ar = a + (size_t)row*HID;
  const float* wr = w + (size_t)j*HID;
  float s = b[j];
  for (int k=0;k<HID;k+=8){
    float fa[8];
    unpack8(*(const uint4*)(ar+k), fa);
    float4 w0 = *(const float4*)(wr + k);
    float4 w1 = *(const float4*)(wr + k + 4);
    s += fa[0]*w0.x + fa[1]*w0.y + fa[2]*w0.z + fa[3]*w0.w
       + fa[4]*w1.x + fa[5]*w1.y + fa[6]*w1.z + fa[7]*w1.w;
  }
  out[g] = s;
}

// ---------------------------------------------------------------------------

extern "C" void kernel_launch(void* const* d_in, const int* in_sizes, int n_in,
                              void* d_out, int out_size, void* d_ws, size_t ws_size,
                              hipStream_t stream)
{
  const float* x   = (const float*)d_in[0];
  const int*   ei  = (const int*)d_in[1];
  const int E = in_sizes[1] / 2;
  const int* srcp = ei;
  const int* dstp = ei + E;

  const float* miw0 = (const float*)d_in[2];
  const float* mib0 = (const float*)d_in[3];
  const float* miw1 = (const float*)d_in[4];
  const float* mib1 = (const float*)d_in[5];
  const float* wih0 = (const float*)d_in[6];
  const float* whh0 = (const float*)d_in[7];
  const float* bih0 = (const float*)d_in[8];
  const float* bhh0 = (const float*)d_in[9];
  const float* wih1 = (const float*)d_in[10];
  const float* whh1 = (const float*)d_in[11];
  const float* bih1 = (const float*)d_in[12];
  const float* bhh1 = (const float*)d_in[13];
  const float* g_wl[2]   = {(const float*)d_in[14], (const float*)d_in[22]};
  const float* g_bl[2]   = {(const float*)d_in[15], (const float*)d_in[23]};
  const float* g_wr[2]   = {(const float*)d_in[16], (const float*)d_in[24]};
  const float* g_br[2]   = {(const float*)d_in[17], (const float*)d_in[25]};
  const float* g_att[2]  = {(const float*)d_in[18], (const float*)d_in[26]};
  const float* g_bias[2] = {(const float*)d_in[19], (const float*)d_in[27]};
  const float* g_pw[2]   = {(const float*)d_in[20], (const float*)d_in[28]};
  const float* g_pb[2]   = {(const float*)d_in[21], (const float*)d_in[29]};
  const float* mow0 = (const float*)d_in[30];
  const float* mob0 = (const float*)d_in[31];
  const float* mow1 = (const float*)d_in[32];
  const float* mob1 = (const float*)d_in[33];
  (void)n_in; (void)out_size; (void)ws_size;

  // ---- workspace layout ----
  char* base = (char*)d_ws;
  size_t off = 0;
  auto carve = [&](size_t n)->char*{
    char* p = base + off;
    off = (off + n + 255) & ~(size_t)255;
    return p;
  };
  char*  X0r = carve((size_t)TLEN*NNODES*HID*2);   // 61,440,000
  bf16*  zf  = (bf16*)carve((size_t)NNODES*HID*2);
  float* Wp  = (float*)carve(HID*INDIM*4);
  float* bp  = (float*)carve(HID*4);
  float* bsum= (float*)carve(2*GDIM*4);
  float* gblr= (float*)carve(2*1024*4);
  bf16*  wbf = (bf16*)carve((size_t)671744*2);
  int*   offsb = (int*)carve((size_t)(NNODES+1)*4);
  int*   curs  = (int*)carve((size_t)NNODES*4);
  int*   srcs  = (int*)carve((size_t)E*4);
  int*   deg   = (int*)carve((size_t)NNODES*4);
  bf16*  agg   = (bf16*)carve((size_t)NNODES*GDIM*2);

  // wbf sub-pointers (conv_w_k chunk order)
  const bf16* wih0b = wbf + 0;
  const bf16* whh0b = wbf + 65536;
  const bf16* wih1b = wbf + 131072;
  const bf16* whh1b = wbf + 196608;
  const bf16* wlr0b = wbf + 262144;   // wl0|wr0 contiguous [1024,128]
  const bf16* pw0b  = wbf + 393216;
  const bf16* wlr1b = wbf + 458752;   // wl1|wr1 contiguous
  const bf16* pw1b  = wbf + 589824;
  const bf16* mow0b = wbf + 655360;
  const bf16* wlrb[2] = {wlr0b, wlr1b};
  const bf16* pwb[2]  = {pw0b, pw1b};

  // X0 region aliases (holds X0, then h1 in-place, dead after LSTM)
  bf16* X0 = (bf16*)X0r;
  bf16* xc = (bf16*)X0r;                      // [10000,1024] = xl|xr
  bf16* z2 = (bf16*)(X0r + 20480000);
  bf16* z3 = (bf16*)(X0r + 23040000);
  bf16* o0 = (bf16*)(X0r + 25600000);

  // ---- prep ----
  conv_w_k<<<2624, 256, 0, stream>>>(wih0, whh0, wih1, whh1,
                                     g_wl[0], g_wr[0], g_pw[0],
                                     g_wl[1], g_wr[1], g_pw[1], mow0, wbf);
  prep_w_k<<<1, 256, 0, stream>>>(miw0, mib0, miw1, mib1,
                                  bih0, bhh0, bih1, bhh1,
                                  g_bl[0], g_br[0], g_bl[1], g_br[1],
                                  Wp, bp, bsum, gblr);
  hipMemsetAsync(deg, 0, (size_t)NNODES*4, stream);

  // ---- MLP in ----
  mlp_in_k<<<(TLEN*NNODES)/64, 256, 0, stream>>>(x, Wp, bp, X0);

  // ---- CSR build ----
  deg_count_k<<<(E+255)/256, 256, 0, stream>>>(dstp, deg, E);
  scan_k<<<1, 256, 0, stream>>>(deg, offsb, curs, NNODES);
  fill_k<<<(E+255)/256, 256, 0, stream>>>(srcp, dstp, curs, srcs, E);

  // ---- LSTM: layer 1 (h1 in-place over X0), then layer 2. M=16 -> 625 blocks ----
  const int NBL = NNODES / 16;   // 625
  lstm_half<1><<<NBL, 512, 0, stream>>>(X0, wih0b, whh0b, bsum, nullptr);
  lstm_half<0><<<NBL, 512, 0, stream>>>(X0, wih1b, whh1b, bsum + GDIM, zf);

  // ---- GAT layers ----
  const bf16* zin = zf;
  bf16* zouts[2] = {z2, z3};
  const int NB64 = (NNODES + 63) / 64;   // 157 blocks
  for (int l=0; l<2; l++){
    gemm_bt<0><<<dim3(79,8), 256, 0, stream>>>(zin, wlrb[l], gblr + l*1024, xc, NNODES, 1024, HID);
    gat_onl<<<(NNODES+3)/4, 256, 0, stream>>>(offsb, srcs, xc, g_att[l], g_bias[l], agg);
    gemm_bt64<1><<<NB64, 256, 0, stream>>>(agg, pwb[l], g_pb[l], zouts[l], NNODES, GDIM);
    zin = zouts[l];
  }

  // ---- MLP out ----
  gemm_bt64<1><<<NB64, 256, 0, stream>>>(z3, mow0b, mob0, o0, NNODES, HID);
  mlp_final_k<<<(NNODES*24+255)/256, 256, 0, stream>>>(o0, mow1, mob1, (float*)d_out);
}

// Round 14
// 605.973 us; speedup vs baseline: 1.1246x; 1.0069x over previous
//
#include <hip/hip_runtime.h>
#include <hip/hip_bf16.h>

#define NNODES 10000
#define TLEN 24
#define INDIM 16
#define HID 128
#define GDIM 512   // 4*HID (LSTM gates) == HEADS*HID (GAT)

typedef __hip_bfloat16 bf16;
typedef short v8s __attribute__((ext_vector_type(8)));
typedef float v4f __attribute__((ext_vector_type(4)));

__device__ inline float u2f(unsigned u){ return __uint_as_float(u); }

__device__ inline void unpack8(uint4 v, float* f){
  f[0]=u2f(v.x<<16); f[1]=u2f(v.x&0xFFFF0000u);
  f[2]=u2f(v.y<<16); f[3]=u2f(v.y&0xFFFF0000u);
  f[4]=u2f(v.z<<16); f[5]=u2f(v.z&0xFFFF0000u);
  f[6]=u2f(v.w<<16); f[7]=u2f(v.w&0xFFFF0000u);
}

// fast device transcendentals (v_exp_f32 + v_rcp_f32; inf-safe)
__device__ inline float fsig(float x){
  return __builtin_amdgcn_rcpf(1.f + __expf(-x));
}
__device__ inline float ftanh(float x){
  float t = __expf(-2.f*fabsf(x));           // in (0,1], no overflow
  float r = (1.f - t) * __builtin_amdgcn_rcpf(1.f + t);
  return copysignf(r, x);
}

// ---------------------------------------------------------------------------
// Convert 11 f32 weight matrices (MFMA B-operands) to bf16; also zeroes the
// CSR degree array (runs before deg_count in stream order).
// Order: wih0,whh0,wih1,whh1, wl0,wr0,pw0, wl1,wr1,pw1 (65536 ea), mow0 (16384).
// ---------------------------------------------------------------------------
__global__ __launch_bounds__(256) void conv_w_k(
    const float* s0, const float* s1, const float* s2, const float* s3,
    const float* s4, const float* s5, const float* s6, const float* s7,
    const float* s8, const float* s9, const float* s10,
    bf16* __restrict__ dst, int* __restrict__ deg)
{
  int idx = blockIdx.x*256 + threadIdx.x;
  if (idx < NNODES) deg[idx] = 0;
  if (idx >= 671744) return;
  int c = idx >> 16;
  float v;
  if (c < 10){
    const float* srcs[10] = {s0,s1,s2,s3,s4,s5,s6,s7,s8,s9};
    v = srcs[c][idx & 0xFFFF];
  } else {
    v = s10[idx - 655360];
  }
  dst[idx] = __float2bfloat16(v);
}

// ---------------------------------------------------------------------------
// Prep: folded MLP-in weights (f32), presummed LSTM biases, concat GAT biases.
// ---------------------------------------------------------------------------
__global__ void prep_w_k(
    const float* __restrict__ miw0, const float* __restrict__ mib0,
    const float* __restrict__ miw1, const float* __restrict__ mib1,
    const float* __restrict__ bih0, const float* __restrict__ bhh0,
    const float* __restrict__ bih1, const float* __restrict__ bhh1,
    const float* __restrict__ bl0, const float* __restrict__ br0,
    const float* __restrict__ bl1, const float* __restrict__ br1,
    float* __restrict__ Wp, float* __restrict__ bp,
    float* __restrict__ bsum, float* __restrict__ gblr)
{
  int t = threadIdx.x;
  for (int idx = t; idx < HID*INDIM; idx += 256){
    int j = idx >> 4, d = idx & 15;
    float s = 0.f;
    for (int k=0;k<HID;k++) s += miw1[j*HID+k] * miw0[k*INDIM+d];
    Wp[idx] = s;
  }
  for (int j = t; j < HID; j += 256){
    float s = mib1[j];
    for (int k=0;k<HID;k++) s += miw1[j*HID+k] * mib0[k];
    bp[j] = s;
  }
  for (int i = t; i < GDIM; i += 256){
    bsum[i]        = bih0[i] + bhh0[i];
    bsum[GDIM + i] = bih1[i] + bhh1[i];
  }
  for (int i = t; i < GDIM; i += 256){
    gblr[i]          = bl0[i];
    gblr[GDIM + i]   = br0[i];
    gblr[1024 + i]   = bl1[i];
    gblr[1536 + i]   = br1[i];
  }
}

// ---------------------------------------------------------------------------
// MLP-in: 64-row x-tile in LDS, W row in registers. Grid 3750.
// ---------------------------------------------------------------------------
__global__ __launch_bounds__(256) void mlp_in_k(
    const float* __restrict__ x, const float* __restrict__ Wp,
    const float* __restrict__ bp, bf16* __restrict__ X0)
{
  __shared__ __align__(16) float xs[64*16];
  const int tid = threadIdx.x;
  const int m0 = blockIdx.x*64;
  {
    int row = tid >> 2, q = tid & 3;
    int m = m0 + row;
    int t = m / NNODES, n = m - t*NNODES;
    float4 v = *(const float4*)(x + ((size_t)n*TLEN + t)*INDIM + q*4);
    *(float4*)(xs + row*16 + q*4) = v;
  }
  const int j = tid & 127;
  const int half = tid >> 7;
  const float* wr = Wp + j*INDIM;
  float4 w0 = *(const float4*)(wr);
  float4 w1 = *(const float4*)(wr + 4);
  float4 w2 = *(const float4*)(wr + 8);
  float4 w3 = *(const float4*)(wr + 12);
  float bj = bp[j];
  __syncthreads();
  #pragma unroll 4
  for (int mi=0; mi<32; mi++){
    int row = mi*2 + half;
    const float* xr = xs + row*16;
    float4 a0 = *(const float4*)(xr);
    float4 a1 = *(const float4*)(xr + 4);
    float4 a2 = *(const float4*)(xr + 8);
    float4 a3 = *(const float4*)(xr + 12);
    float s = bj
      + a0.x*w0.x + a0.y*w0.y + a0.z*w0.z + a0.w*w0.w
      + a1.x*w1.x + a1.y*w1.y + a1.z*w1.z + a1.w*w1.w
      + a2.x*w2.x + a2.y*w2.y + a2.z*w2.z + a2.w*w2.w
      + a3.x*w3.x + a3.y*w3.y + a3.z*w3.z + a3.w*w3.w;
    s = s > 0.f ? s : 0.f;
    X0[(size_t)(m0+row)*HID + j] = __float2bfloat16(s);
  }
}

// ---------------------------------------------------------------------------
// LSTM, one layer, 24 steps. M=16 rows/block, 625 blocks. Register-resident
// weights, EARLY X prefetch, dbuf LDS h, rolled t-loop. (r13-best, unchanged.)
// ---------------------------------------------------------------------------
template<int WRITE_ALL>
__global__ __launch_bounds__(512) void lstm_half(
    const bf16* __restrict__ Xin, const bf16* __restrict__ Wih,
    const bf16* __restrict__ Whh, const float* __restrict__ bias,
    bf16* __restrict__ out)
{
  __shared__ __align__(16) bf16 hsA[16*136];
  __shared__ __align__(16) bf16 hsB[16*136];
  const int tid = threadIdx.x;
  const int lane = tid & 63, w = tid >> 6;
  const int r16 = lane & 15, quad = lane >> 4;
  const int m0 = blockIdx.x*16;

  v8s wbi[4][4], wbh[4][4];
  #pragma unroll
  for (int g=0; g<4; g++)
    #pragma unroll
    for (int kc=0; kc<4; kc++){
      size_t o = (size_t)(g*HID + w*16 + r16)*HID + kc*32 + quad*8;
      wbi[g][kc] = *(const v8s*)(Wih + o);
      wbh[g][kc] = *(const v8s*)(Whh + o);
    }
  float bg[4];
  #pragma unroll
  for (int g=0; g<4; g++) bg[g] = bias[g*HID + w*16 + r16];

  const size_t rowoff = (size_t)(m0 + r16) * HID;

  float c[4];
  #pragma unroll
  for (int i=0;i<4;i++) c[i] = 0.f;

  for (int i = tid; i < 272; i += 512){
    *(uint4*)((char*)hsA + i*16) = make_uint4(0,0,0,0);
    *(uint4*)((char*)hsB + i*16) = make_uint4(0,0,0,0);
  }

  v8s ax[4];
  #pragma unroll
  for (int kc=0; kc<4; kc++)
    ax[kc] = *(const v8s*)(Xin + rowoff + kc*32 + quad*8);

  __syncthreads();

  #pragma unroll 1
  for (int t=0; t<TLEN; t++){
    bf16* hrd = (t & 1) ? hsA : hsB;
    bf16* hwr = (t & 1) ? hsB : hsA;

    v4f acc[4];
    #pragma unroll
    for (int g=0;g<4;g++) acc[g] = (v4f)0.f;

    #pragma unroll
    for (int kc=0; kc<4; kc++)
      #pragma unroll
      for (int g=0;g<4;g++)
        acc[g] = __builtin_amdgcn_mfma_f32_16x16x32_bf16(ax[kc], wbi[g][kc], acc[g], 0, 0, 0);

    {
      int tn = t+1 < TLEN ? t+1 : TLEN-1;
      const bf16* Xn = Xin + (size_t)tn*NNODES*HID;
      #pragma unroll
      for (int kc=0; kc<4; kc++)
        ax[kc] = *(const v8s*)(Xn + rowoff + kc*32 + quad*8);
    }

    #pragma unroll
    for (int kc=0; kc<4; kc++){
      v8s av = *(const v8s*)(hrd + r16*136 + kc*32 + quad*8);
      #pragma unroll
      for (int g=0;g<4;g++)
        acc[g] = __builtin_amdgcn_mfma_f32_16x16x32_bf16(av, wbh[g][kc], acc[g], 0, 0, 0);
    }

    #pragma unroll
    for (int r=0;r<4;r++){
      int lrow = quad*4 + r;
      float iv = acc[0][r] + bg[0];
      float fv = acc[1][r] + bg[1];
      float gv = acc[2][r] + bg[2];
      float ov = acc[3][r] + bg[3];
      float ig = fsig(iv), fg = fsig(fv);
      float gg = ftanh(gv), og = fsig(ov);
      float cn = fg*c[r] + ig*gg;
      c[r] = cn;
      hwr[lrow*136 + w*16 + r16] = __float2bfloat16(og*ftanh(cn));
    }
    __syncthreads();

    if (WRITE_ALL){
      bf16* dst = (bf16*)(Xin + (size_t)t*NNODES*HID);
      for (int i = tid; i < 256; i += 512){
        int row = i >> 4, c8 = (i & 15) * 8;
        *(uint4*)(dst + (size_t)(m0+row)*HID + c8) = *(const uint4*)(hwr + row*136 + c8);
      }
    }
  }

  if (!WRITE_ALL){
    const bf16* hfin = ((TLEN-1) & 1) ? hsB : hsA;
    for (int i = tid; i < 256; i += 512){
      int row = i >> 4, c8 = (i & 15) * 8;
      *(uint4*)(out + (size_t)(m0+row)*HID + c8) = *(const uint4*)(hfin + row*136 + c8);
    }
  }
}

// ---------------------------------------------------------------------------
// Generic bf16 GEMM: C[M,N] = act(A[M,K] @ B[N,K]^T + bias_f32[N]), bf16 out.
// ---------------------------------------------------------------------------
template<int ACT>
__global__ __launch_bounds__(256) void gemm_bt(
    const bf16* __restrict__ A, const bf16* __restrict__ B,
    const float* __restrict__ bias, bf16* __restrict__ C,
    int M, int N, int K)
{
  __shared__ __align__(16) bf16 As[128*40];
  __shared__ __align__(16) bf16 Bs[128*40];
  const int tid = threadIdx.x;
  const int m0 = blockIdx.x*128, n0 = blockIdx.y*128;
  const int lane = tid & 63, wave = tid >> 6;
  const int r16 = lane & 15, quad = lane >> 4;

  v4f acc[2][8];
  #pragma unroll
  for (int a=0;a<2;a++)
    #pragma unroll
    for (int b=0;b<8;b++) acc[a][b] = (v4f)0.f;

  for (int k0=0; k0<K; k0+=32){
    #pragma unroll
    for (int i=0;i<2;i++){
      int li = tid + i*256;
      int row = li >> 2, q4 = li & 3;
      uint4 va = make_uint4(0,0,0,0);
      int gm = m0 + row;
      if (gm < M) va = *(const uint4*)(A + (size_t)gm*K + k0 + q4*8);
      *(uint4*)(As + row*40 + q4*8) = va;
      uint4 vb = make_uint4(0,0,0,0);
      int gn = n0 + row;
      if (gn < N) vb = *(const uint4*)(B + (size_t)gn*K + k0 + q4*8);
      *(uint4*)(Bs + row*40 + q4*8) = vb;
    }
    __syncthreads();
    v8s av[2], bv[8];
    #pragma unroll
    for (int mi=0;mi<2;mi++)
      av[mi] = *(const v8s*)(As + (wave*32 + mi*16 + r16)*40 + quad*8);
    #pragma unroll
    for (int ni=0;ni<8;ni++)
      bv[ni] = *(const v8s*)(Bs + (ni*16 + r16)*40 + quad*8);
    #pragma unroll
    for (int mi=0;mi<2;mi++)
      #pragma unroll
      for (int ni=0;ni<8;ni++)
        acc[mi][ni] = __builtin_amdgcn_mfma_f32_16x16x32_bf16(av[mi], bv[ni], acc[mi][ni], 0, 0, 0);
    __syncthreads();
  }

  #pragma unroll
  for (int mi=0;mi<2;mi++){
    #pragma unroll
    for (int r=0;r<4;r++){
      int row = m0 + wave*32 + mi*16 + quad*4 + r;
      if (row >= M) continue;
      #pragma unroll
      for (int ni=0;ni<8;ni++){
        int col = n0 + ni*16 + r16;
        float v = acc[mi][ni][r] + bias[col];
        if (ACT == 1) v = v > 0.f ? v : 0.f;
        C[(size_t)row*N + col] = __float2bfloat16(v);
      }
    }
  }
}

// ---------------------------------------------------------------------------
// 64-row-tile GEMM for N=128 outputs (projection / mlp-out).
// ---------------------------------------------------------------------------
template<int ACT>
__global__ __launch_bounds__(256) void gemm_bt64(
    const bf16* __restrict__ A, const bf16* __restrict__ B,
    const float* __restrict__ bias, bf16* __restrict__ C,
    int M, int K)   // N == 128
{
  __shared__ __align__(16) bf16 As[64*40];
  __shared__ __align__(16) bf16 Bs[128*40];
  const int tid = threadIdx.x;
  const int m0 = blockIdx.x*64;
  const int lane = tid & 63, wave = tid >> 6;
  const int r16 = lane & 15, quad = lane >> 4;

  v4f acc[8];
  #pragma unroll
  for (int b=0;b<8;b++) acc[b] = (v4f)0.f;

  for (int k0=0; k0<K; k0+=32){
    {
      int row = tid >> 2, q4 = tid & 3;
      uint4 va = make_uint4(0,0,0,0);
      int gm = m0 + row;
      if (gm < M) va = *(const uint4*)(A + (size_t)gm*K + k0 + q4*8);
      *(uint4*)(As + row*40 + q4*8) = va;
    }
    #pragma unroll
    for (int i=0;i<2;i++){
      int li = tid + i*256;
      int row = li >> 2, q4 = li & 3;
      uint4 vb = *(const uint4*)(B + (size_t)row*K + k0 + q4*8);
      *(uint4*)(Bs + row*40 + q4*8) = vb;
    }
    __syncthreads();
    v8s av, bv[8];
    av = *(const v8s*)(As + (wave*16 + r16)*40 + quad*8);
    #pragma unroll
    for (int ni=0;ni<8;ni++)
      bv[ni] = *(const v8s*)(Bs + (ni*16 + r16)*40 + quad*8);
    #pragma unroll
    for (int ni=0;ni<8;ni++)
      acc[ni] = __builtin_amdgcn_mfma_f32_16x16x32_bf16(av, bv[ni], acc[ni], 0, 0, 0);
    __syncthreads();
  }

  #pragma unroll
  for (int r=0;r<4;r++){
    int row = m0 + wave*16 + quad*4 + r;
    if (row >= M) continue;
    #pragma unroll
    for (int ni=0;ni<8;ni++){
      int col = ni*16 + r16;
      float v = acc[ni][r] + bias[col];
      if (ACT == 1) v = v > 0.f ? v : 0.f;
      C[(size_t)row*HID + col] = __float2bfloat16(v);
    }
  }
}

// ---------------------------------------------------------------------------
// CSR build (payload = resolved src id)
// ---------------------------------------------------------------------------
__global__ void deg_count_k(const int* __restrict__ dst, int* __restrict__ deg, int E){
  int e = blockIdx.x*256 + threadIdx.x;
  if (e < E){
    unsigned d = (unsigned)dst[e];
    if (d < (unsigned)NNODES) atomicAdd(&deg[d], 1);
  }
}

__global__ void scan_k(const int* __restrict__ deg, int* __restrict__ offs,
                       int* __restrict__ cursor, int n)
{
  __shared__ int part[256];
  __shared__ int base[256];
  int t = threadIdx.x;
  int lo = t*40, hi = lo+40;
  if (lo > n) lo = n;
  if (hi > n) hi = n;
  int s = 0;
  for (int i=lo;i<hi;i++) s += deg[i];
  part[t] = s;
  __syncthreads();
  if (t == 0){
    int run=0;
    for (int i=0;i<256;i++){ base[i]=run; run+=part[i]; }
    offs[n] = run;
  }
  __syncthreads();
  int run = base[t];
  for (int i=lo;i<hi;i++){ offs[i]=run; cursor[i]=run; run += deg[i]; }
}

__global__ void fill_k(const int* __restrict__ src, const int* __restrict__ dst,
                       int* __restrict__ cursor, int* __restrict__ srcs, int E){
  int e = blockIdx.x*256 + threadIdx.x;
  if (e < E){
    unsigned d = (unsigned)dst[e];
    if (d < (unsigned)NNODES){
      int p = atomicAdd(&cursor[d], 1);
      unsigned s = (unsigned)src[e];
      srcs[p] = (s < (unsigned)NNODES) ? (int)s : 0;
    }
  }
}

// ---------------------------------------------------------------------------
// GATv2 online-softmax fused score+aggregate, SOFTWARE-PIPELINED: the next
// edge's 1KB row-gather is issued before computing the current edge, so the
// ~60-100cyc edge compute overlaps the next gather's L2/HBM latency.
// 1 wave/dst node.
// ---------------------------------------------------------------------------
__global__ __launch_bounds__(256) void gat_onl(
    const int* __restrict__ offs, const int* __restrict__ srcs,
    const bf16* __restrict__ xc, const float* __restrict__ att,
    const float* __restrict__ gbias, bf16* __restrict__ agg)
{
  int d = blockIdx.x*4 + (threadIdx.x >> 6);
  if (d >= NNODES) return;
  int lane = threadIdx.x & 63;
  float fr[8];
  unpack8(*(const uint4*)(xc + (size_t)d*1024 + 512 + lane*8), fr);
  float4 a0 = *(const float4*)(att + lane*8);
  float4 a1 = *(const float4*)(att + lane*8 + 4);
  float fa[8] = {a0.x,a0.y,a0.z,a0.w,a1.x,a1.y,a1.z,a1.w};
  int i0 = offs[d], i1 = offs[d+1];

  float m = -3.4e38f, den = 0.f;
  float acc[8] = {0,0,0,0,0,0,0,0};

  if (i0 < i1){
    uint4 raw = *(const uint4*)(xc + (size_t)srcs[i0]*1024 + lane*8);
    for (int i=i0; i<i1; i++){
      uint4 nxt;
      if (i+1 < i1)
        nxt = *(const uint4*)(xc + (size_t)srcs[i+1]*1024 + lane*8);
      float fl[8];
      unpack8(raw, fl);
      float p = 0.f;
      #pragma unroll
      for (int q=0;q<8;q++){
        float v = fl[q] + fr[q];
        v = v > 0.f ? v : 0.2f*v;
        p += v*fa[q];
      }
      p += __shfl_xor(p, 1); p += __shfl_xor(p, 2);
      p += __shfl_xor(p, 4); p += __shfl_xor(p, 8);
      float mn = fmaxf(m, p);
      float corr = __expf(m - mn);
      float w = __expf(p - mn);
      den = den*corr + w;
      #pragma unroll
      for (int q=0;q<8;q++) acc[q] = acc[q]*corr + w*fl[q];
      m = mn;
      raw = nxt;
    }
  }
  float r = 1.f/(den + 1e-16f);
  float4 b0 = *(const float4*)(gbias + lane*8);
  float4 b1 = *(const float4*)(gbias + lane*8 + 4);
  float fb[8] = {b0.x,b0.y,b0.z,b0.w,b1.x,b1.y,b1.z,b1.w};
  #pragma unroll
  for (int q=0;q<8;q++)
    agg[(size_t)d*GDIM + lane*8 + q] = __float2bfloat16(acc[q]*r + fb[q]);
}

// ---------------------------------------------------------------------------
// Final linear (N=24): f32 weights, f32 out.
// ---------------------------------------------------------------------------
__global__ __launch_bounds__(256) void mlp_final_k(
    const bf16* __restrict__ a, const float* __restrict__ w,
    const float* __restrict__ b, float* __restrict__ out)
{
  int g = blockIdx.x*256 + threadIdx.x;
  if (g >= NNODES*24) return;
  int j = g % 24;
  int row = g / 24;
  const bf16* ar = a + (size_t)row*HID;
  const float* wr = w + (size_t)j*HID;
  float s = b[j];
  for (int k=0;k<HID;k+=8){
    float fa[8];
    unpack8(*(const uint4*)(ar+k), fa);
    float4 w0 = *(const float4*)(wr + k);
    float4 w1 = *(const float4*)(wr + k + 4);
    s += fa[0]*w0.x + fa[1]*w0.y + fa[2]*w0.z + fa[3]*w0.w
       + fa[4]*w1.x + fa[5]*w1.y + fa[6]*w1.z + fa[7]*w1.w;
  }
  out[g] = s;
}

// ---------------------------------------------------------------------------

extern "C" void kernel_launch(void* const* d_in, const int* in_sizes, int n_in,
                              void* d_out, int out_size, void* d_ws, size_t ws_size,
                              hipStream_t stream)
{
  const float* x   = (const float*)d_in[0];
  const int*   ei  = (const int*)d_in[1];
  const int E = in_sizes[1] / 2;
  const int* srcp = ei;
  const int* dstp = ei + E;

  const float* miw0 = (const float*)d_in[2];
  const float* mib0 = (const float*)d_in[3];
  const float* miw1 = (const float*)d_in[4];
  const float* mib1 = (const float*)d_in[5];
  const float* wih0 = (const float*)d_in[6];
  const float* whh0 = (const float*)d_in[7];
  const float* bih0 = (const float*)d_in[8];
  const float* bhh0 = (const float*)d_in[9];
  const float* wih1 = (const float*)d_in[10];
  const float* whh1 = (const float*)d_in[11];
  const float* bih1 = (const float*)d_in[12];
  const float* bhh1 = (const float*)d_in[13];
  const float* g_wl[2]   = {(const float*)d_in[14], (const float*)d_in[22]};
  const float* g_bl[2]   = {(const float*)d_in[15], (const float*)d_in[23]};
  const float* g_wr[2]   = {(const float*)d_in[16], (const float*)d_in[24]};
  const float* g_br[2]   = {(const float*)d_in[17], (const float*)d_in[25]};
  const float* g_att[2]  = {(const float*)d_in[18], (const float*)d_in[26]};
  const float* g_bias[2] = {(const float*)d_in[19], (const float*)d_in[27]};
  const float* g_pw[2]   = {(const float*)d_in[20], (const float*)d_in[28]};
  const float* g_pb[2]   = {(const float*)d_in[21], (const float*)d_in[29]};
  const float* mow0 = (const float*)d_in[30];
  const float* mob0 = (const float*)d_in[31];
  const float* mow1 = (const float*)d_in[32];
  const float* mob1 = (const float*)d_in[33];
  (void)n_in; (void)out_size; (void)ws_size;

  // ---- workspace layout ----
  char* base = (char*)d_ws;
  size_t off = 0;
  auto carve = [&](size_t n)->char*{
    char* p = base + off;
    off = (off + n + 255) & ~(size_t)255;
    return p;
  };
  char*  X0r = carve((size_t)TLEN*NNODES*HID*2);   // 61,440,000
  bf16*  zf  = (bf16*)carve((size_t)NNODES*HID*2);
  float* Wp  = (float*)carve(HID*INDIM*4);
  float* bp  = (float*)carve(HID*4);
  float* bsum= (float*)carve(2*GDIM*4);
  float* gblr= (float*)carve(2*1024*4);
  bf16*  wbf = (bf16*)carve((size_t)671744*2);
  int*   offsb = (int*)carve((size_t)(NNODES+1)*4);
  int*   curs  = (int*)carve((size_t)NNODES*4);
  int*   srcs  = (int*)carve((size_t)E*4);
  int*   deg   = (int*)carve((size_t)NNODES*4);
  bf16*  agg   = (bf16*)carve((size_t)NNODES*GDIM*2);

  // wbf sub-pointers (conv_w_k chunk order)
  const bf16* wih0b = wbf + 0;
  const bf16* whh0b = wbf + 65536;
  const bf16* wih1b = wbf + 131072;
  const bf16* whh1b = wbf + 196608;
  const bf16* wlr0b = wbf + 262144;   // wl0|wr0 contiguous [1024,128]
  const bf16* pw0b  = wbf + 393216;
  const bf16* wlr1b = wbf + 458752;   // wl1|wr1 contiguous
  const bf16* pw1b  = wbf + 589824;
  const bf16* mow0b = wbf + 655360;
  const bf16* wlrb[2] = {wlr0b, wlr1b};
  const bf16* pwb[2]  = {pw0b, pw1b};

  // X0 region aliases (holds X0, then h1 in-place, dead after LSTM)
  bf16* X0 = (bf16*)X0r;
  bf16* xc = (bf16*)X0r;                      // [10000,1024] = xl|xr
  bf16* z2 = (bf16*)(X0r + 20480000);
  bf16* z3 = (bf16*)(X0r + 23040000);
  bf16* o0 = (bf16*)(X0r + 25600000);

  // ---- prep (also zeroes deg) ----
  conv_w_k<<<2624, 256, 0, stream>>>(wih0, whh0, wih1, whh1,
                                     g_wl[0], g_wr[0], g_pw[0],
                                     g_wl[1], g_wr[1], g_pw[1], mow0, wbf, deg);
  prep_w_k<<<1, 256, 0, stream>>>(miw0, mib0, miw1, mib1,
                                  bih0, bhh0, bih1, bhh1,
                                  g_bl[0], g_br[0], g_bl[1], g_br[1],
                                  Wp, bp, bsum, gblr);

  // ---- MLP in ----
  mlp_in_k<<<(TLEN*NNODES)/64, 256, 0, stream>>>(x, Wp, bp, X0);

  // ---- CSR build ----
  deg_count_k<<<(E+255)/256, 256, 0, stream>>>(dstp, deg, E);
  scan_k<<<1, 256, 0, stream>>>(deg, offsb, curs, NNODES);
  fill_k<<<(E+255)/256, 256, 0, stream>>>(srcp, dstp, curs, srcs, E);

  // ---- LSTM: layer 1 (h1 in-place over X0), then layer 2. M=16 -> 625 blocks ----
  const int NBL = NNODES / 16;   // 625
  lstm_half<1><<<NBL, 512, 0, stream>>>(X0, wih0b, whh0b, bsum, nullptr);
  lstm_half<0><<<NBL, 512, 0, stream>>>(X0, wih1b, whh1b, bsum + GDIM, zf);

  // ---- GAT layers ----
  const bf16* zin = zf;
  bf16* zouts[2] = {z2, z3};
  const int NB64 = (NNODES + 63) / 64;   // 157 blocks
  for (int l=0; l<2; l++){
    gemm_bt<0><<<dim3(79,8), 256, 0, stream>>>(zin, wlrb[l], gblr + l*1024, xc, NNODES, 1024, HID);
    gat_onl<<<(NNODES+3)/4, 256, 0, stream>>>(offsb, srcs, xc, g_att[l], g_bias[l], agg);
    gemm_bt64<1><<<NB64, 256, 0, stream>>>(agg, pwb[l], g_pb[l], zouts[l], NNODES, GDIM);
    zin = zouts[l];
  }

  // ---- MLP out ----
  gemm_bt64<1><<<NB64, 256, 0, stream>>>(z3, mow0b, mob0, o0, NNODES, HID);
  mlp_final_k<<<(NNODES*24+255)/256, 256, 0, stream>>>(o0, mow1, mob1, (float*)d_out);
}

// Round 15
// 578.027 us; speedup vs baseline: 1.1790x; 1.0483x over previous
//
#include <hip/hip_runtime.h>
#include <hip/hip_bf16.h>

#define NNODES 10000
#define TLEN 24
#define INDIM 16
#define HID 128
#define GDIM 512   // 4*HID (LSTM gates) == HEADS*HID (GAT)

typedef __hip_bfloat16 bf16;
typedef short v8s __attribute__((ext_vector_type(8)));
typedef float v4f __attribute__((ext_vector_type(4)));

__device__ inline float u2f(unsigned u){ return __uint_as_float(u); }

__device__ inline void unpack8(uint4 v, float* f){
  f[0]=u2f(v.x<<16); f[1]=u2f(v.x&0xFFFF0000u);
  f[2]=u2f(v.y<<16); f[3]=u2f(v.y&0xFFFF0000u);
  f[4]=u2f(v.z<<16); f[5]=u2f(v.z&0xFFFF0000u);
  f[6]=u2f(v.w<<16); f[7]=u2f(v.w&0xFFFF0000u);
}

// fast device transcendentals (v_exp_f32 + v_rcp_f32; inf-safe)
__device__ inline float fsig(float x){
  return __builtin_amdgcn_rcpf(1.f + __expf(-x));
}
__device__ inline float ftanh(float x){
  float t = __expf(-2.f*fabsf(x));           // in (0,1], no overflow
  float r = (1.f - t) * __builtin_amdgcn_rcpf(1.f + t);
  return copysignf(r, x);
}

// ---------------------------------------------------------------------------
// Convert 11 f32 weight matrices (MFMA B-operands) to bf16; also zeroes the
// CSR degree array.
// Order: wih0,whh0,wih1,whh1, wl0,wr0,pw0, wl1,wr1,pw1 (65536 ea), mow0 (16384).
// ---------------------------------------------------------------------------
__global__ __launch_bounds__(256) void conv_w_k(
    const float* s0, const float* s1, const float* s2, const float* s3,
    const float* s4, const float* s5, const float* s6, const float* s7,
    const float* s8, const float* s9, const float* s10,
    bf16* __restrict__ dst, int* __restrict__ deg)
{
  int idx = blockIdx.x*256 + threadIdx.x;
  if (idx < NNODES) deg[idx] = 0;
  if (idx >= 671744) return;
  int c = idx >> 16;
  float v;
  if (c < 10){
    const float* srcs[10] = {s0,s1,s2,s3,s4,s5,s6,s7,s8,s9};
    v = srcs[c][idx & 0xFFFF];
  } else {
    v = s10[idx - 655360];
  }
  dst[idx] = __float2bfloat16(v);
}

// ---------------------------------------------------------------------------
// Prep, PARALLELIZED across 9 blocks (same per-element FP order as before):
// blocks 0..7: Wp = miw1@miw0 fold (2048 outputs, 1/thread).
// block 8: bp, bsum, gblr.
// ---------------------------------------------------------------------------
__global__ __launch_bounds__(256) void prep_w_k(
    const float* __restrict__ miw0, const float* __restrict__ mib0,
    const float* __restrict__ miw1, const float* __restrict__ mib1,
    const float* __restrict__ bih0, const float* __restrict__ bhh0,
    const float* __restrict__ bih1, const float* __restrict__ bhh1,
    const float* __restrict__ bl0, const float* __restrict__ br0,
    const float* __restrict__ bl1, const float* __restrict__ br1,
    float* __restrict__ Wp, float* __restrict__ bp,
    float* __restrict__ bsum, float* __restrict__ gblr)
{
  int t = threadIdx.x;
  int b = blockIdx.x;
  if (b < 8){
    int idx = b*256 + t;          // < 2048 = HID*INDIM
    int j = idx >> 4, d = idx & 15;
    float s = 0.f;
    for (int k=0;k<HID;k++) s += miw1[j*HID+k] * miw0[k*INDIM+d];
    Wp[idx] = s;
    return;
  }
  // block 8: bp + bsum + gblr
  if (t < HID){
    float s = mib1[t];
    for (int k=0;k<HID;k++) s += miw1[t*HID+k] * mib0[k];
    bp[t] = s;
  }
  for (int i = t; i < GDIM; i += 256){
    bsum[i]        = bih0[i] + bhh0[i];
    bsum[GDIM + i] = bih1[i] + bhh1[i];
  }
  for (int i = t; i < GDIM; i += 256){
    gblr[i]          = bl0[i];
    gblr[GDIM + i]   = br0[i];
    gblr[1024 + i]   = bl1[i];
    gblr[1536 + i]   = br1[i];
  }
}

// ---------------------------------------------------------------------------
// MLP-in: 64-row x-tile in LDS, W row in registers. Grid 3750.
// ---------------------------------------------------------------------------
__global__ __launch_bounds__(256) void mlp_in_k(
    const float* __restrict__ x, const float* __restrict__ Wp,
    const float* __restrict__ bp, bf16* __restrict__ X0)
{
  __shared__ __align__(16) float xs[64*16];
  const int tid = threadIdx.x;
  const int m0 = blockIdx.x*64;
  {
    int row = tid >> 2, q = tid & 3;
    int m = m0 + row;
    int t = m / NNODES, n = m - t*NNODES;
    float4 v = *(const float4*)(x + ((size_t)n*TLEN + t)*INDIM + q*4);
    *(float4*)(xs + row*16 + q*4) = v;
  }
  const int j = tid & 127;
  const int half = tid >> 7;
  const float* wr = Wp + j*INDIM;
  float4 w0 = *(const float4*)(wr);
  float4 w1 = *(const float4*)(wr + 4);
  float4 w2 = *(const float4*)(wr + 8);
  float4 w3 = *(const float4*)(wr + 12);
  float bj = bp[j];
  __syncthreads();
  #pragma unroll 4
  for (int mi=0; mi<32; mi++){
    int row = mi*2 + half;
    const float* xr = xs + row*16;
    float4 a0 = *(const float4*)(xr);
    float4 a1 = *(const float4*)(xr + 4);
    float4 a2 = *(const float4*)(xr + 8);
    float4 a3 = *(const float4*)(xr + 12);
    float s = bj
      + a0.x*w0.x + a0.y*w0.y + a0.z*w0.z + a0.w*w0.w
      + a1.x*w1.x + a1.y*w1.y + a1.z*w1.z + a1.w*w1.w
      + a2.x*w2.x + a2.y*w2.y + a2.z*w2.z + a2.w*w2.w
      + a3.x*w3.x + a3.y*w3.y + a3.z*w3.z + a3.w*w3.w;
    s = s > 0.f ? s : 0.f;
    X0[(size_t)(m0+row)*HID + j] = __float2bfloat16(s);
  }
}

// ---------------------------------------------------------------------------
// LSTM, one layer, 24 steps. M=16 rows/block, 625 blocks. (r13-best.)
// ---------------------------------------------------------------------------
template<int WRITE_ALL>
__global__ __launch_bounds__(512) void lstm_half(
    const bf16* __restrict__ Xin, const bf16* __restrict__ Wih,
    const bf16* __restrict__ Whh, const float* __restrict__ bias,
    bf16* __restrict__ out)
{
  __shared__ __align__(16) bf16 hsA[16*136];
  __shared__ __align__(16) bf16 hsB[16*136];
  const int tid = threadIdx.x;
  const int lane = tid & 63, w = tid >> 6;
  const int r16 = lane & 15, quad = lane >> 4;
  const int m0 = blockIdx.x*16;

  v8s wbi[4][4], wbh[4][4];
  #pragma unroll
  for (int g=0; g<4; g++)
    #pragma unroll
    for (int kc=0; kc<4; kc++){
      size_t o = (size_t)(g*HID + w*16 + r16)*HID + kc*32 + quad*8;
      wbi[g][kc] = *(const v8s*)(Wih + o);
      wbh[g][kc] = *(const v8s*)(Whh + o);
    }
  float bg[4];
  #pragma unroll
  for (int g=0; g<4; g++) bg[g] = bias[g*HID + w*16 + r16];

  const size_t rowoff = (size_t)(m0 + r16) * HID;

  float c[4];
  #pragma unroll
  for (int i=0;i<4;i++) c[i] = 0.f;

  for (int i = tid; i < 272; i += 512){
    *(uint4*)((char*)hsA + i*16) = make_uint4(0,0,0,0);
    *(uint4*)((char*)hsB + i*16) = make_uint4(0,0,0,0);
  }

  v8s ax[4];
  #pragma unroll
  for (int kc=0; kc<4; kc++)
    ax[kc] = *(const v8s*)(Xin + rowoff + kc*32 + quad*8);

  __syncthreads();

  #pragma unroll 1
  for (int t=0; t<TLEN; t++){
    bf16* hrd = (t & 1) ? hsA : hsB;
    bf16* hwr = (t & 1) ? hsB : hsA;

    v4f acc[4];
    #pragma unroll
    for (int g=0;g<4;g++) acc[g] = (v4f)0.f;

    #pragma unroll
    for (int kc=0; kc<4; kc++)
      #pragma unroll
      for (int g=0;g<4;g++)
        acc[g] = __builtin_amdgcn_mfma_f32_16x16x32_bf16(ax[kc], wbi[g][kc], acc[g], 0, 0, 0);

    {
      int tn = t+1 < TLEN ? t+1 : TLEN-1;
      const bf16* Xn = Xin + (size_t)tn*NNODES*HID;
      #pragma unroll
      for (int kc=0; kc<4; kc++)
        ax[kc] = *(const v8s*)(Xn + rowoff + kc*32 + quad*8);
    }

    #pragma unroll
    for (int kc=0; kc<4; kc++){
      v8s av = *(const v8s*)(hrd + r16*136 + kc*32 + quad*8);
      #pragma unroll
      for (int g=0;g<4;g++)
        acc[g] = __builtin_amdgcn_mfma_f32_16x16x32_bf16(av, wbh[g][kc], acc[g], 0, 0, 0);
    }

    #pragma unroll
    for (int r=0;r<4;r++){
      int lrow = quad*4 + r;
      float iv = acc[0][r] + bg[0];
      float fv = acc[1][r] + bg[1];
      float gv = acc[2][r] + bg[2];
      float ov = acc[3][r] + bg[3];
      float ig = fsig(iv), fg = fsig(fv);
      float gg = ftanh(gv), og = fsig(ov);
      float cn = fg*c[r] + ig*gg;
      c[r] = cn;
      hwr[lrow*136 + w*16 + r16] = __float2bfloat16(og*ftanh(cn));
    }
    __syncthreads();

    if (WRITE_ALL){
      bf16* dst = (bf16*)(Xin + (size_t)t*NNODES*HID);
      for (int i = tid; i < 256; i += 512){
        int row = i >> 4, c8 = (i & 15) * 8;
        *(uint4*)(dst + (size_t)(m0+row)*HID + c8) = *(const uint4*)(hwr + row*136 + c8);
      }
    }
  }

  if (!WRITE_ALL){
    const bf16* hfin = ((TLEN-1) & 1) ? hsB : hsA;
    for (int i = tid; i < 256; i += 512){
      int row = i >> 4, c8 = (i & 15) * 8;
      *(uint4*)(out + (size_t)(m0+row)*HID + c8) = *(const uint4*)(hfin + row*136 + c8);
    }
  }
}

// ---------------------------------------------------------------------------
// Generic bf16 GEMM: C[M,N] = act(A[M,K] @ B[N,K]^T + bias_f32[N]), bf16 out.
// ---------------------------------------------------------------------------
template<int ACT>
__global__ __launch_bounds__(256) void gemm_bt(
    const bf16* __restrict__ A, const bf16* __restrict__ B,
    const float* __restrict__ bias, bf16* __restrict__ C,
    int M, int N, int K)
{
  __shared__ __align__(16) bf16 As[128*40];
  __shared__ __align__(16) bf16 Bs[128*40];
  const int tid = threadIdx.x;
  const int m0 = blockIdx.x*128, n0 = blockIdx.y*128;
  const int lane = tid & 63, wave = tid >> 6;
  const int r16 = lane & 15, quad = lane >> 4;

  v4f acc[2][8];
  #pragma unroll
  for (int a=0;a<2;a++)
    #pragma unroll
    for (int b=0;b<8;b++) acc[a][b] = (v4f)0.f;

  for (int k0=0; k0<K; k0+=32){
    #pragma unroll
    for (int i=0;i<2;i++){
      int li = tid + i*256;
      int row = li >> 2, q4 = li & 3;
      uint4 va = make_uint4(0,0,0,0);
      int gm = m0 + row;
      if (gm < M) va = *(const uint4*)(A + (size_t)gm*K + k0 + q4*8);
      *(uint4*)(As + row*40 + q4*8) = va;
      uint4 vb = make_uint4(0,0,0,0);
      int gn = n0 + row;
      if (gn < N) vb = *(const uint4*)(B + (size_t)gn*K + k0 + q4*8);
      *(uint4*)(Bs + row*40 + q4*8) = vb;
    }
    __syncthreads();
    v8s av[2], bv[8];
    #pragma unroll
    for (int mi=0;mi<2;mi++)
      av[mi] = *(const v8s*)(As + (wave*32 + mi*16 + r16)*40 + quad*8);
    #pragma unroll
    for (int ni=0;ni<8;ni++)
      bv[ni] = *(const v8s*)(Bs + (ni*16 + r16)*40 + quad*8);
    #pragma unroll
    for (int mi=0;mi<2;mi++)
      #pragma unroll
      for (int ni=0;ni<8;ni++)
        acc[mi][ni] = __builtin_amdgcn_mfma_f32_16x16x32_bf16(av[mi], bv[ni], acc[mi][ni], 0, 0, 0);
    __syncthreads();
  }

  #pragma unroll
  for (int mi=0;mi<2;mi++){
    #pragma unroll
    for (int r=0;r<4;r++){
      int row = m0 + wave*32 + mi*16 + quad*4 + r;
      if (row >= M) continue;
      #pragma unroll
      for (int ni=0;ni<8;ni++){
        int col = n0 + ni*16 + r16;
        float v = acc[mi][ni][r] + bias[col];
        if (ACT == 1) v = v > 0.f ? v : 0.f;
        C[(size_t)row*N + col] = __float2bfloat16(v);
      }
    }
  }
}

// ---------------------------------------------------------------------------
// 64-row-tile GEMM for N=128 outputs (GAT projection).
// ---------------------------------------------------------------------------
template<int ACT>
__global__ __launch_bounds__(256) void gemm_bt64(
    const bf16* __restrict__ A, const bf16* __restrict__ B,
    const float* __restrict__ bias, bf16* __restrict__ C,
    int M, int K)   // N == 128
{
  __shared__ __align__(16) bf16 As[64*40];
  __shared__ __align__(16) bf16 Bs[128*40];
  const int tid = threadIdx.x;
  const int m0 = blockIdx.x*64;
  const int lane = tid & 63, wave = tid >> 6;
  const int r16 = lane & 15, quad = lane >> 4;

  v4f acc[8];
  #pragma unroll
  for (int b=0;b<8;b++) acc[b] = (v4f)0.f;

  for (int k0=0; k0<K; k0+=32){
    {
      int row = tid >> 2, q4 = tid & 3;
      uint4 va = make_uint4(0,0,0,0);
      int gm = m0 + row;
      if (gm < M) va = *(const uint4*)(A + (size_t)gm*K + k0 + q4*8);
      *(uint4*)(As + row*40 + q4*8) = va;
    }
    #pragma unroll
    for (int i=0;i<2;i++){
      int li = tid + i*256;
      int row = li >> 2, q4 = li & 3;
      uint4 vb = *(const uint4*)(B + (size_t)row*K + k0 + q4*8);
      *(uint4*)(Bs + row*40 + q4*8) = vb;
    }
    __syncthreads();
    v8s av, bv[8];
    av = *(const v8s*)(As + (wave*16 + r16)*40 + quad*8);
    #pragma unroll
    for (int ni=0;ni<8;ni++)
      bv[ni] = *(const v8s*)(Bs + (ni*16 + r16)*40 + quad*8);
    #pragma unroll
    for (int ni=0;ni<8;ni++)
      acc[ni] = __builtin_amdgcn_mfma_f32_16x16x32_bf16(av, bv[ni], acc[ni], 0, 0, 0);
    __syncthreads();
  }

  #pragma unroll
  for (int r=0;r<4;r++){
    int row = m0 + wave*16 + quad*4 + r;
    if (row >= M) continue;
    #pragma unroll
    for (int ni=0;ni<8;ni++){
      int col = ni*16 + r16;
      float v = acc[ni][r] + bias[col];
      if (ACT == 1) v = v > 0.f ? v : 0.f;
      C[(size_t)row*HID + col] = __float2bfloat16(v);
    }
  }
}

// ---------------------------------------------------------------------------
// MLP-out FUSED: o0 = relu(z3 @ mow0^T + mob0) computed like gemm_bt64, but
// the bf16 tile goes to LDS (identical values to the old global o0), then the
// final N=24 layer runs from LDS with the exact same 8-chunk accumulation
// order as the old mlp_final_k. Saves the o0 HBM round-trip + one launch.
// ---------------------------------------------------------------------------
__global__ __launch_bounds__(256) void mlp_out_fused_k(
    const bf16* __restrict__ A, const bf16* __restrict__ B,
    const float* __restrict__ bias, const float* __restrict__ w1,
    const float* __restrict__ b1, float* __restrict__ out, int M)
{
  __shared__ __align__(16) bf16 As[64*40];
  __shared__ __align__(16) bf16 Bs[128*40];
  __shared__ __align__(16) bf16 o0s[64*136];
  const int tid = threadIdx.x;
  const int m0 = blockIdx.x*64;
  const int lane = tid & 63, wave = tid >> 6;
  const int r16 = lane & 15, quad = lane >> 4;

  v4f acc[8];
  #pragma unroll
  for (int b=0;b<8;b++) acc[b] = (v4f)0.f;

  for (int k0=0; k0<HID; k0+=32){
    {
      int row = tid >> 2, q4 = tid & 3;
      uint4 va = make_uint4(0,0,0,0);
      int gm = m0 + row;
      if (gm < M) va = *(const uint4*)(A + (size_t)gm*HID + k0 + q4*8);
      *(uint4*)(As + row*40 + q4*8) = va;
    }
    #pragma unroll
    for (int i=0;i<2;i++){
      int li = tid + i*256;
      int row = li >> 2, q4 = li & 3;
      uint4 vb = *(const uint4*)(B + (size_t)row*HID + k0 + q4*8);
      *(uint4*)(Bs + row*40 + q4*8) = vb;
    }
    __syncthreads();
    v8s av, bv[8];
    av = *(const v8s*)(As + (wave*16 + r16)*40 + quad*8);
    #pragma unroll
    for (int ni=0;ni<8;ni++)
      bv[ni] = *(const v8s*)(Bs + (ni*16 + r16)*40 + quad*8);
    #pragma unroll
    for (int ni=0;ni<8;ni++)
      acc[ni] = __builtin_amdgcn_mfma_f32_16x16x32_bf16(av, bv[ni], acc[ni], 0, 0, 0);
    __syncthreads();
  }

  // o0 tile -> LDS as bf16 (same values the old path stored to global)
  #pragma unroll
  for (int r=0;r<4;r++){
    int row = wave*16 + quad*4 + r;
    #pragma unroll
    for (int ni=0;ni<8;ni++){
      int col = ni*16 + r16;
      float v = acc[ni][r] + bias[col];
      v = v > 0.f ? v : 0.f;
      o0s[row*136 + col] = __float2bfloat16(v);
    }
  }
  __syncthreads();

  // final: out[row, j] = b1[j] + o0row . w1[j,:]  (same loop shape as before)
  for (int idx = tid; idx < 64*24; idx += 256){
    int row = idx / 24, j = idx - row*24;
    if (m0 + row >= M) continue;
    const bf16* ar = o0s + row*136;
    const float* wr = w1 + j*HID;
    float s = b1[j];
    for (int k=0;k<HID;k+=8){
      float fa[8];
      unpack8(*(const uint4*)(ar+k), fa);
      float4 w0 = *(const float4*)(wr + k);
      float4 w1v = *(const float4*)(wr + k + 4);
      s += fa[0]*w0.x + fa[1]*w0.y + fa[2]*w0.z + fa[3]*w0.w
         + fa[4]*w1v.x + fa[5]*w1v.y + fa[6]*w1v.z + fa[7]*w1v.w;
    }
    out[(size_t)(m0+row)*24 + j] = s;
  }
}

// ---------------------------------------------------------------------------
// CSR build (payload = resolved src id)
// ---------------------------------------------------------------------------
__global__ void deg_count_k(const int* __restrict__ dst, int* __restrict__ deg, int E){
  int e = blockIdx.x*256 + threadIdx.x;
  if (e < E){
    unsigned d = (unsigned)dst[e];
    if (d < (unsigned)NNODES) atomicAdd(&deg[d], 1);
  }
}

__global__ void scan_k(const int* __restrict__ deg, int* __restrict__ offs,
                       int* __restrict__ cursor, int n)
{
  __shared__ int part[256];
  __shared__ int base[256];
  int t = threadIdx.x;
  int lo = t*40, hi = lo+40;
  if (lo > n) lo = n;
  if (hi > n) hi = n;
  int s = 0;
  for (int i=lo;i<hi;i++) s += deg[i];
  part[t] = s;
  __syncthreads();
  if (t == 0){
    int run=0;
    for (int i=0;i<256;i++){ base[i]=run; run+=part[i]; }
    offs[n] = run;
  }
  __syncthreads();
  int run = base[t];
  for (int i=lo;i<hi;i++){ offs[i]=run; cursor[i]=run; run += deg[i]; }
}

__global__ void fill_k(const int* __restrict__ src, const int* __restrict__ dst,
                       int* __restrict__ cursor, int* __restrict__ srcs, int E){
  int e = blockIdx.x*256 + threadIdx.x;
  if (e < E){
    unsigned d = (unsigned)dst[e];
    if (d < (unsigned)NNODES){
      int p = atomicAdd(&cursor[d], 1);
      unsigned s = (unsigned)src[e];
      srcs[p] = (s < (unsigned)NNODES) ? (int)s : 0;
    }
  }
}

// ---------------------------------------------------------------------------
// GATv2 online-softmax fused score+aggregate, distance-2 prefetch pipeline
// (order-identical math). 1 wave/dst node.
// ---------------------------------------------------------------------------
__global__ __launch_bounds__(256) void gat_onl(
    const int* __restrict__ offs, const int* __restrict__ srcs,
    const bf16* __restrict__ xc, const float* __restrict__ att,
    const float* __restrict__ gbias, bf16* __restrict__ agg)
{
  int d = blockIdx.x*4 + (threadIdx.x >> 6);
  if (d >= NNODES) return;
  int lane = threadIdx.x & 63;
  float fr[8];
  unpack8(*(const uint4*)(xc + (size_t)d*1024 + 512 + lane*8), fr);
  float4 a0 = *(const float4*)(att + lane*8);
  float4 a1 = *(const float4*)(att + lane*8 + 4);
  float fa[8] = {a0.x,a0.y,a0.z,a0.w,a1.x,a1.y,a1.z,a1.w};
  int i0 = offs[d], i1 = offs[d+1];

  float m = -3.4e38f, den = 0.f;
  float acc[8] = {0,0,0,0,0,0,0,0};

  if (i0 < i1){
    uint4 r0 = *(const uint4*)(xc + (size_t)srcs[i0]*1024 + lane*8);
    uint4 r1 = r0;
    if (i0+1 < i1) r1 = *(const uint4*)(xc + (size_t)srcs[i0+1]*1024 + lane*8);
    for (int i=i0; i<i1; i++){
      uint4 r2 = r1;
      if (i+2 < i1) r2 = *(const uint4*)(xc + (size_t)srcs[i+2]*1024 + lane*8);
      float fl[8];
      unpack8(r0, fl);
      float p = 0.f;
      #pragma unroll
      for (int q=0;q<8;q++){
        float v = fl[q] + fr[q];
        v = v > 0.f ? v : 0.2f*v;
        p += v*fa[q];
      }
      p += __shfl_xor(p, 1); p += __shfl_xor(p, 2);
      p += __shfl_xor(p, 4); p += __shfl_xor(p, 8);
      float mn = fmaxf(m, p);
      float corr = __expf(m - mn);
      float w = __expf(p - mn);
      den = den*corr + w;
      #pragma unroll
      for (int q=0;q<8;q++) acc[q] = acc[q]*corr + w*fl[q];
      m = mn;
      r0 = r1; r1 = r2;
    }
  }
  float r = 1.f/(den + 1e-16f);
  float4 b0 = *(const float4*)(gbias + lane*8);
  float4 b1 = *(const float4*)(gbias + lane*8 + 4);
  float fb[8] = {b0.x,b0.y,b0.z,b0.w,b1.x,b1.y,b1.z,b1.w};
  #pragma unroll
  for (int q=0;q<8;q++)
    agg[(size_t)d*GDIM + lane*8 + q] = __float2bfloat16(acc[q]*r + fb[q]);
}

// ---------------------------------------------------------------------------

extern "C" void kernel_launch(void* const* d_in, const int* in_sizes, int n_in,
                              void* d_out, int out_size, void* d_ws, size_t ws_size,
                              hipStream_t stream)
{
  const float* x   = (const float*)d_in[0];
  const int*   ei  = (const int*)d_in[1];
  const int E = in_sizes[1] / 2;
  const int* srcp = ei;
  const int* dstp = ei + E;

  const float* miw0 = (const float*)d_in[2];
  const float* mib0 = (const float*)d_in[3];
  const float* miw1 = (const float*)d_in[4];
  const float* mib1 = (const float*)d_in[5];
  const float* wih0 = (const float*)d_in[6];
  const float* whh0 = (const float*)d_in[7];
  const float* bih0 = (const float*)d_in[8];
  const float* bhh0 = (const float*)d_in[9];
  const float* wih1 = (const float*)d_in[10];
  const float* whh1 = (const float*)d_in[11];
  const float* bih1 = (const float*)d_in[12];
  const float* bhh1 = (const float*)d_in[13];
  const float* g_wl[2]   = {(const float*)d_in[14], (const float*)d_in[22]};
  const float* g_bl[2]   = {(const float*)d_in[15], (const float*)d_in[23]};
  const float* g_wr[2]   = {(const float*)d_in[16], (const float*)d_in[24]};
  const float* g_br[2]   = {(const float*)d_in[17], (const float*)d_in[25]};
  const float* g_att[2]  = {(const float*)d_in[18], (const float*)d_in[26]};
  const float* g_bias[2] = {(const float*)d_in[19], (const float*)d_in[27]};
  const float* g_pw[2]   = {(const float*)d_in[20], (const float*)d_in[28]};
  const float* g_pb[2]   = {(const float*)d_in[21], (const float*)d_in[29]};
  const float* mow0 = (const float*)d_in[30];
  const float* mob0 = (const float*)d_in[31];
  const float* mow1 = (const float*)d_in[32];
  const float* mob1 = (const float*)d_in[33];
  (void)n_in; (void)out_size; (void)ws_size;

  // ---- workspace layout ----
  char* base = (char*)d_ws;
  size_t off = 0;
  auto carve = [&](size_t n)->char*{
    char* p = base + off;
    off = (off + n + 255) & ~(size_t)255;
    return p;
  };
  char*  X0r = carve((size_t)TLEN*NNODES*HID*2);   // 61,440,000
  bf16*  zf  = (bf16*)carve((size_t)NNODES*HID*2);
  float* Wp  = (float*)carve(HID*INDIM*4);
  float* bp  = (float*)carve(HID*4);
  float* bsum= (float*)carve(2*GDIM*4);
  float* gblr= (float*)carve(2*1024*4);
  bf16*  wbf = (bf16*)carve((size_t)671744*2);
  int*   offsb = (int*)carve((size_t)(NNODES+1)*4);
  int*   curs  = (int*)carve((size_t)NNODES*4);
  int*   srcs  = (int*)carve((size_t)E*4);
  int*   deg   = (int*)carve((size_t)NNODES*4);
  bf16*  agg   = (bf16*)carve((size_t)NNODES*GDIM*2);

  // wbf sub-pointers (conv_w_k chunk order)
  const bf16* wih0b = wbf + 0;
  const bf16* whh0b = wbf + 65536;
  const bf16* wih1b = wbf + 131072;
  const bf16* whh1b = wbf + 196608;
  const bf16* wlr0b = wbf + 262144;   // wl0|wr0 contiguous [1024,128]
  const bf16* pw0b  = wbf + 393216;
  const bf16* wlr1b = wbf + 458752;   // wl1|wr1 contiguous
  const bf16* pw1b  = wbf + 589824;
  const bf16* mow0b = wbf + 655360;
  const bf16* wlrb[2] = {wlr0b, wlr1b};
  const bf16* pwb[2]  = {pw0b, pw1b};

  // X0 region aliases (holds X0, then h1 in-place, dead after LSTM)
  bf16* X0 = (bf16*)X0r;
  bf16* xc = (bf16*)X0r;                      // [10000,1024] = xl|xr
  bf16* z2 = (bf16*)(X0r + 20480000);
  bf16* z3 = (bf16*)(X0r + 23040000);

  // ---- prep (also zeroes deg) ----
  conv_w_k<<<2624, 256, 0, stream>>>(wih0, whh0, wih1, whh1,
                                     g_wl[0], g_wr[0], g_pw[0],
                                     g_wl[1], g_wr[1], g_pw[1], mow0, wbf, deg);
  prep_w_k<<<9, 256, 0, stream>>>(miw0, mib0, miw1, mib1,
                                  bih0, bhh0, bih1, bhh1,
                                  g_bl[0], g_br[0], g_bl[1], g_br[1],
                                  Wp, bp, bsum, gblr);

  // ---- MLP in ----
  mlp_in_k<<<(TLEN*NNODES)/64, 256, 0, stream>>>(x, Wp, bp, X0);

  // ---- CSR build ----
  deg_count_k<<<(E+255)/256, 256, 0, stream>>>(dstp, deg, E);
  scan_k<<<1, 256, 0, stream>>>(deg, offsb, curs, NNODES);
  fill_k<<<(E+255)/256, 256, 0, stream>>>(srcp, dstp, curs, srcs, E);

  // ---- LSTM: layer 1 (h1 in-place over X0), then layer 2. M=16 -> 625 blocks ----
  const int NBL = NNODES / 16;   // 625
  lstm_half<1><<<NBL, 512, 0, stream>>>(X0, wih0b, whh0b, bsum, nullptr);
  lstm_half<0><<<NBL, 512, 0, stream>>>(X0, wih1b, whh1b, bsum + GDIM, zf);

  // ---- GAT layers ----
  const bf16* zin = zf;
  bf16* zouts[2] = {z2, z3};
  const int NB64 = (NNODES + 63) / 64;   // 157 blocks
  for (int l=0; l<2; l++){
    gemm_bt<0><<<dim3(79,8), 256, 0, stream>>>(zin, wlrb[l], gblr + l*1024, xc, NNODES, 1024, HID);
    gat_onl<<<(NNODES+3)/4, 256, 0, stream>>>(offsb, srcs, xc, g_att[l], g_bias[l], agg);
    gemm_bt64<1><<<NB64, 256, 0, stream>>>(agg, pwb[l], g_pb[l], zouts[l], NNODES, GDIM);
    zin = zouts[l];
  }

  // ---- MLP out (fused GEMM + final layer) ----
  mlp_out_fused_k<<<NB64, 256, 0, stream>>>(z3, mow0b, mob0, mow1, mob1,
                                            (float*)d_out, NNODES);
}